// Round 11
// baseline (1027.533 us; speedup 1.0000x reference)
//
#include <hip/hip_runtime.h>

#define MTOK 32768   // 8*4096 tokens
#define CIN  512     // in_ch
#define EMB  256     // emb_ch
#define NCODE 1024
#define VQ   3
#define DELTA 2e-3f  // certified margin; worst-case approx score-diff error ~3e-4

typedef short s16x8 __attribute__((ext_vector_type(8)));
typedef float f32x4 __attribute__((ext_vector_type(4)));
typedef unsigned short u16;

static __device__ __forceinline__ u16 f2bf(float x) {
    unsigned int u = __float_as_uint(x);
    u += 0x7FFF + ((u >> 16) & 1);          // RNE
    return (u16)(u >> 16);
}
static __device__ __forceinline__ float bf2f(u16 h) {
    return __uint_as_float(((unsigned int)h) << 16);
}

// ---------------- init ----------------
__global__ void init_k(double* loss_acc, int* cnt) {
    loss_acc[0] = 0.0;  // sum of min-dists (znorm parts + score parts)
    loss_acc[1] = 0.0;  // sum (z - z_q)^2
    #pragma unroll
    for (int i = 0; i < 8; ++i) cnt[i] = 0;   // [0..2]=pair counts, [3..5]=full counts
}

// ---------------- codebook prep: ||v||^2 (fp64/fp32) + bf16 hi/lo split ----------------
__global__ __launch_bounds__(64) void prep_cb_k(const float* __restrict__ cbs,
                                                double* __restrict__ vnorm64,
                                                float* __restrict__ vnorm32,
                                                u16* __restrict__ cbh,
                                                u16* __restrict__ cbl) {
    int s = blockIdx.x;                       // 0 .. 3*NCODE-1
    const float* row = cbs + (size_t)s * EMB;
    double acc = 0.0;
    for (int k = threadIdx.x; k < EMB; k += 64) {
        float v = row[k];
        double vd = (double)v; acc += vd * vd;
        u16 h = f2bf(v);
        u16 l = f2bf(v - bf2f(h));
        cbh[(size_t)s * EMB + k] = h;
        cbl[(size_t)s * EMB + k] = l;
    }
    #pragma unroll
    for (int off = 32; off > 0; off >>= 1) acc += __shfl_down(acc, off, 64);
    if (threadIdx.x == 0) { vnorm64[s] = acc; vnorm32[s] = (float)acc; }
}

// ---------------- W_in bf16 hi/lo split ----------------
__global__ __launch_bounds__(256) void prep_w_k(const float* __restrict__ W_in,
                                                u16* __restrict__ wh,
                                                u16* __restrict__ wl) {
    int i = blockIdx.x * 256 + threadIdx.x;   // < VQ*EMB*CIN
    float v = W_in[i];
    u16 h = f2bf(v);
    wh[i] = h;
    wl[i] = f2bf(v - bf2f(h));
}

// ---------------- W_in transpose: WinT[s][k][e] = W_in[s][e][k] (exact fp32) ----------------
__global__ __launch_bounds__(256) void prep_wt_k(const float* __restrict__ W_in,
                                                 float* __restrict__ WinT) {
    int i = blockIdx.x * 256 + threadIdx.x;   // < VQ*EMB*CIN
    int s = i / (EMB * CIN);
    int rem = i - s * (EMB * CIN);
    int e = rem / CIN;
    int k = rem - e * CIN;
    WinT[(size_t)s * CIN * EMB + (size_t)k * EMB + e] = W_in[i];
}

// ---------------- T[s] = cb[s] @ W_out[s]^T  (fp64 acc, fp32 store) ----------------
__global__ __launch_bounds__(256) void prep_T_k(const float* __restrict__ cbs,
                                                const float* __restrict__ Wout,
                                                float* __restrict__ T) {
    const int stage = blockIdx.z;
    const float* A = cbs  + (size_t)stage * NCODE * EMB;
    const float* B = Wout + (size_t)stage * CIN * EMB;
    float* C = T + (size_t)stage * NCODE * CIN;
    __shared__ float As[64][33];
    __shared__ float Bs[64][33];
    const int tid = threadIdx.x;
    const int ty = tid >> 4, tx = tid & 15;
    const int m0 = blockIdx.x * 64;
    const int n0 = blockIdx.y * 64;
    const int lrow = tid >> 5, lcol = tid & 31;
    double acc[4][4];
    #pragma unroll
    for (int i = 0; i < 4; ++i)
        #pragma unroll
        for (int j = 0; j < 4; ++j) acc[i][j] = 0.0;

    for (int k0 = 0; k0 < EMB; k0 += 32) {
        __syncthreads();
        #pragma unroll
        for (int t = 0; t < 8; ++t) {
            int r = lrow + 8 * t;
            As[r][lcol] = A[(size_t)(m0 + r) * EMB + k0 + lcol];
            Bs[r][lcol] = B[(size_t)(n0 + r) * EMB + k0 + lcol];
        }
        __syncthreads();
        #pragma unroll
        for (int k = 0; k < 32; ++k) {
            double a[4], b[4];
            #pragma unroll
            for (int i = 0; i < 4; ++i) a[i] = (double)As[ty * 4 + i][k];
            #pragma unroll
            for (int j = 0; j < 4; ++j) b[j] = (double)Bs[tx * 4 + j][k];
            #pragma unroll
            for (int i = 0; i < 4; ++i)
                #pragma unroll
                for (int j = 0; j < 4; ++j) acc[i][j] += a[i] * b[j];
        }
    }
    #pragma unroll
    for (int i = 0; i < 4; ++i) {
        float4 v = make_float4((float)acc[i][0], (float)acc[i][1],
                               (float)acc[i][2], (float)acc[i][3]);
        *reinterpret_cast<float4*>(&C[(size_t)(m0 + ty * 4 + i) * CIN + n0 + tx * 4]) = v;
    }
}

// ---------------- zi = (z - zq) @ W_in^T via bf16-split MFMA, dbuf LDS W ----------------
__global__ __launch_bounds__(256, 2) void zi_mfma_k(const float* __restrict__ z,
                                                    const float* __restrict__ zq,
                                                    const u16* __restrict__ wh,
                                                    const u16* __restrict__ wl,
                                                    float* __restrict__ zi,
                                                    double* __restrict__ loss_acc,
                                                    int stage0) {
    __shared__ __align__(16) u16 swh[2][16][520];
    __shared__ __align__(16) u16 swl[2][16][520];
    const int tid = threadIdx.x;
    const int w = tid >> 6;
    const int l = tid & 63;
    const int col = l & 15;
    const int g = l >> 4;
    const int mw = blockIdx.x * 64 + w * 16;
    const int sr = tid >> 4, sq = tid & 15;

    // A fragments: bf16 hi/lo split of residual row (mw+col), k = kc*32 + g*8 + j
    s16x8 ah[16], al[16];
    {
        const float* zr = z  + (size_t)(mw + col) * CIN + g * 8;
        const float* qr = zq + (size_t)(mw + col) * CIN + g * 8;
        #pragma unroll
        for (int kc = 0; kc < 16; ++kc) {
            float4 f0 = *reinterpret_cast<const float4*>(zr + kc * 32);
            float4 f1 = *reinterpret_cast<const float4*>(zr + kc * 32 + 4);
            float f[8] = {f0.x, f0.y, f0.z, f0.w, f1.x, f1.y, f1.z, f1.w};
            if (!stage0) {
                float4 q0 = *reinterpret_cast<const float4*>(qr + kc * 32);
                float4 q1 = *reinterpret_cast<const float4*>(qr + kc * 32 + 4);
                f[0] -= q0.x; f[1] -= q0.y; f[2] -= q0.z; f[3] -= q0.w;
                f[4] -= q1.x; f[5] -= q1.y; f[6] -= q1.z; f[7] -= q1.w;
            }
            #pragma unroll
            for (int j = 0; j < 8; ++j) {
                u16 h = f2bf(f[j]);
                u16 lo = f2bf(f[j] - bf2f(h));
                ah[kc][j] = (short)h; al[kc][j] = (short)lo;
            }
        }
    }

    const u16* gh = wh + (size_t)sr * CIN + sq * 8;
    const u16* gl = wl + (size_t)sr * CIN + sq * 8;
    uint4 h0, h1, h2, h3, l0, l1, l2, l3;
#define ZLOAD(NT) do { const u16* th = gh + (size_t)(NT) * (16 * CIN);                \
    const u16* tl = gl + (size_t)(NT) * (16 * CIN);                                   \
    h0 = *(const uint4*)(th);        h1 = *(const uint4*)(th + 128);                  \
    h2 = *(const uint4*)(th + 256);  h3 = *(const uint4*)(th + 384);                  \
    l0 = *(const uint4*)(tl);        l1 = *(const uint4*)(tl + 128);                  \
    l2 = *(const uint4*)(tl + 256);  l3 = *(const uint4*)(tl + 384); } while (0)
#define ZWRITE(P) do {                                                                \
    *(uint4*)&swh[P][sr][sq * 8]       = h0;  *(uint4*)&swh[P][sr][sq * 8 + 128] = h1;\
    *(uint4*)&swh[P][sr][sq * 8 + 256] = h2;  *(uint4*)&swh[P][sr][sq * 8 + 384] = h3;\
    *(uint4*)&swl[P][sr][sq * 8]       = l0;  *(uint4*)&swl[P][sr][sq * 8 + 128] = l1;\
    *(uint4*)&swl[P][sr][sq * 8 + 256] = l2;  *(uint4*)&swl[P][sr][sq * 8 + 384] = l3;\
    } while (0)
    ZLOAD(0); ZWRITE(0); ZLOAD(1);

    double zn = 0.0;
    for (int nt = 0; nt < 16; ++nt) {
        __syncthreads();                         // buf[nt&1] ready; prev reads done
        const int p = nt & 1;
        if (nt + 1 < 16) ZWRITE((nt + 1) & 1);
        if (nt + 2 < 16) ZLOAD(nt + 2);
        f32x4 a0 = {0.f, 0.f, 0.f, 0.f};
        f32x4 a1 = {0.f, 0.f, 0.f, 0.f};
        f32x4 a2 = {0.f, 0.f, 0.f, 0.f};
        #pragma unroll
        for (int kc = 0; kc < 16; ++kc) {
            s16x8 Bh = *(const s16x8*)&swh[p][col][g * 8 + kc * 32];
            s16x8 Bl = *(const s16x8*)&swl[p][col][g * 8 + kc * 32];
            a0 = __builtin_amdgcn_mfma_f32_16x16x32_bf16(ah[kc], Bh, a0, 0, 0, 0);
            a1 = __builtin_amdgcn_mfma_f32_16x16x32_bf16(al[kc], Bh, a1, 0, 0, 0);
            a2 = __builtin_amdgcn_mfma_f32_16x16x32_bf16(ah[kc], Bl, a2, 0, 0, 0);
        }
        #pragma unroll
        for (int r = 0; r < 4; ++r) {
            float v = a0[r] + a1[r] + a2[r];
            zi[(size_t)(mw + g * 4 + r) * EMB + nt * 16 + col] = v;
            zn += (double)v * (double)v;
        }
    }
#undef ZLOAD
#undef ZWRITE
    #pragma unroll
    for (int off = 32; off > 0; off >>= 1) zn += __shfl_down(zn, off, 64);
    if (l == 0) atomicAdd(loss_acc, zn);
}

// ---------------- MFMA bf16-split prefilter, dbuf LDS, 32 tokens/wave, top-3 ----------------
// Block = 4 waves x 32 tokens = 128 tokens; every B-tile LDS read feeds 2 token-sets.
__global__ __launch_bounds__(256, 1) void pref_k(const float* __restrict__ zi,
                                                 const u16* __restrict__ cbh,
                                                 const u16* __restrict__ cbl,
                                                 const float* __restrict__ vnorm32,
                                                 int* __restrict__ idx,
                                                 int* __restrict__ idx_sum,
                                                 float* __restrict__ mind,
                                                 int* __restrict__ flagged,
                                                 int* __restrict__ cnt,
                                                 int* __restrict__ fullList,
                                                 int* __restrict__ cntF,
                                                 int* __restrict__ cand2,
                                                 double* __restrict__ loss_acc,
                                                 int stage0, int cumprod) {
    __shared__ __align__(16) u16 sbh[2][16][264];
    __shared__ __align__(16) u16 sbl[2][16][264];
    __shared__ double loss_s[16];
    const int tid = threadIdx.x;
    const int w = tid >> 6;
    const int l = tid & 63;
    const int col = l & 15;
    const int g = l >> 4;
    const int mw = blockIdx.x * 128 + w * 32;    // 32 tokens per wave
    const int sr = tid >> 4, sq = tid & 15;

    s16x8 ah0[8], al0[8], ah1[8], al1[8];
    {
        const float* zr0 = zi + (size_t)(mw + col) * EMB + g * 8;
        const float* zr1 = zi + (size_t)(mw + 16 + col) * EMB + g * 8;
        #pragma unroll
        for (int kc = 0; kc < 8; ++kc) {
            float4 f0 = *reinterpret_cast<const float4*>(zr0 + kc * 32);
            float4 f1 = *reinterpret_cast<const float4*>(zr0 + kc * 32 + 4);
            float f[8] = {f0.x, f0.y, f0.z, f0.w, f1.x, f1.y, f1.z, f1.w};
            #pragma unroll
            for (int j = 0; j < 8; ++j) {
                u16 h = f2bf(f[j]);
                u16 lo = f2bf(f[j] - bf2f(h));
                ah0[kc][j] = (short)h;
                al0[kc][j] = (short)lo;
            }
            float4 e0 = *reinterpret_cast<const float4*>(zr1 + kc * 32);
            float4 e1 = *reinterpret_cast<const float4*>(zr1 + kc * 32 + 4);
            float e[8] = {e0.x, e0.y, e0.z, e0.w, e1.x, e1.y, e1.z, e1.w};
            #pragma unroll
            for (int j = 0; j < 8; ++j) {
                u16 h = f2bf(e[j]);
                u16 lo = f2bf(e[j] - bf2f(h));
                ah1[kc][j] = (short)h;
                al1[kc][j] = (short)lo;
            }
        }
    }

    float b1a[4], b2a[4], b3a[4], b1b[4], b2b[4], b3b[4];
    int   i1a[4], i2a[4], i1b[4], i2b[4];
    #pragma unroll
    for (int r = 0; r < 4; ++r) {
        b1a[r] = b2a[r] = b3a[r] = 1e30f; i1a[r] = i2a[r] = 0;
        b1b[r] = b2b[r] = b3b[r] = 1e30f; i1b[r] = i2b[r] = 0;
    }

    const u16* gh = cbh + (size_t)sr * EMB + sq * 8;
    const u16* gl = cbl + (size_t)sr * EMB + sq * 8;
    uint4 h0, h1, l0, l1;
#define PLOAD(CT) do { const u16* th = gh + (size_t)(CT) * (16 * EMB);                \
    const u16* tl = gl + (size_t)(CT) * (16 * EMB);                                   \
    h0 = *(const uint4*)(th);  h1 = *(const uint4*)(th + 128);                        \
    l0 = *(const uint4*)(tl);  l1 = *(const uint4*)(tl + 128); } while (0)
#define PWRITE(P) do {                                                                \
    *(uint4*)&sbh[P][sr][sq * 8] = h0;  *(uint4*)&sbh[P][sr][sq * 8 + 128] = h1;      \
    *(uint4*)&sbl[P][sr][sq * 8] = l0;  *(uint4*)&sbl[P][sr][sq * 8 + 128] = l1;      \
    } while (0)
    PLOAD(0); PWRITE(0); PLOAD(1);

    for (int ct = 0; ct < 64; ++ct) {
        __syncthreads();                         // buf[ct&1] ready; prev reads done
        const int p = ct & 1;
        if (ct + 1 < 64) PWRITE((ct + 1) & 1);
        if (ct + 2 < 64) PLOAD(ct + 2);
        const float vn = vnorm32[ct * 16 + col];
        f32x4 a00 = {0.f, 0.f, 0.f, 0.f}, a01 = {0.f, 0.f, 0.f, 0.f}, a02 = {0.f, 0.f, 0.f, 0.f};
        f32x4 a10 = {0.f, 0.f, 0.f, 0.f}, a11 = {0.f, 0.f, 0.f, 0.f}, a12 = {0.f, 0.f, 0.f, 0.f};
        #pragma unroll
        for (int kc = 0; kc < 8; ++kc) {
            s16x8 Bh = *(const s16x8*)&sbh[p][col][g * 8 + kc * 32];
            s16x8 Bl = *(const s16x8*)&sbl[p][col][g * 8 + kc * 32];
            a00 = __builtin_amdgcn_mfma_f32_16x16x32_bf16(ah0[kc], Bh, a00, 0, 0, 0);
            a10 = __builtin_amdgcn_mfma_f32_16x16x32_bf16(ah1[kc], Bh, a10, 0, 0, 0);
            a01 = __builtin_amdgcn_mfma_f32_16x16x32_bf16(al0[kc], Bh, a01, 0, 0, 0);
            a11 = __builtin_amdgcn_mfma_f32_16x16x32_bf16(al1[kc], Bh, a11, 0, 0, 0);
            a02 = __builtin_amdgcn_mfma_f32_16x16x32_bf16(ah0[kc], Bl, a02, 0, 0, 0);
            a12 = __builtin_amdgcn_mfma_f32_16x16x32_bf16(ah1[kc], Bl, a12, 0, 0, 0);
        }
        #pragma unroll
        for (int r = 0; r < 4; ++r) {
            int c = ct * 16 + col;
            float sa = vn - 2.f * (a00[r] + a01[r] + a02[r]);
            if (sa < b1a[r]) { b3a[r] = b2a[r]; b2a[r] = b1a[r]; i2a[r] = i1a[r]; b1a[r] = sa; i1a[r] = c; }
            else if (sa < b2a[r]) { b3a[r] = b2a[r]; b2a[r] = sa; i2a[r] = c; }
            else b3a[r] = fminf(b3a[r], sa);
            float sb = vn - 2.f * (a10[r] + a11[r] + a12[r]);
            if (sb < b1b[r]) { b3b[r] = b2b[r]; b2b[r] = b1b[r]; i2b[r] = i1b[r]; b1b[r] = sb; i1b[r] = c; }
            else if (sb < b2b[r]) { b3b[r] = b2b[r]; b2b[r] = sb; i2b[r] = c; }
            else b3b[r] = fminf(b3b[r], sb);
        }
    }
#undef PLOAD
#undef PWRITE

    // cross-lane top-3 merge over the 16 lanes of each token group (both sets)
#define MERGE16(B1, B2, B3, I1, I2) do {                                              \
    _Pragma("unroll")                                                                 \
    for (int off = 1; off < 16; off <<= 1) {                                          \
        _Pragma("unroll")                                                             \
        for (int r = 0; r < 4; ++r) {                                                 \
            float c1 = __shfl_xor(B1[r], off, 64);                                    \
            int   j1 = __shfl_xor(I1[r], off, 64);                                    \
            float c2 = __shfl_xor(B2[r], off, 64);                                    \
            int   j2 = __shfl_xor(I2[r], off, 64);                                    \
            float c3 = __shfl_xor(B3[r], off, 64);                                    \
            float nb1, nb2, nb3; int ni1, ni2;                                        \
            if (c1 < B1[r] || (c1 == B1[r] && j1 < I1[r])) {                          \
                nb1 = c1; ni1 = j1;                                                   \
                if (B1[r] < c2 || (B1[r] == c2 && I1[r] < j2)) {                      \
                    nb2 = B1[r]; ni2 = I1[r]; nb3 = fminf(B2[r], c2);                 \
                } else {                                                              \
                    nb2 = c2; ni2 = j2; nb3 = fminf(B1[r], c3);                       \
                }                                                                     \
            } else {                                                                  \
                nb1 = B1[r]; ni1 = I1[r];                                             \
                if (c1 < B2[r] || (c1 == B2[r] && j1 < I2[r])) {                      \
                    nb2 = c1; ni2 = j1; nb3 = fminf(B2[r], c2);                       \
                } else {                                                              \
                    nb2 = B2[r]; ni2 = I2[r]; nb3 = fminf(c1, B3[r]);                 \
                }                                                                     \
            }                                                                         \
            B1[r] = nb1; B2[r] = nb2; B3[r] = nb3; I1[r] = ni1; I2[r] = ni2;          \
        }                                                                             \
    }                                                                                 \
} while (0)
    MERGE16(b1a, b2a, b3a, i1a, i2a);
    MERGE16(b1b, b2b, b3b, i1b, i2b);
#undef MERGE16

    if (col == 0) {
        double lsum = 0.0;
        #pragma unroll
        for (int r = 0; r < 4; ++r) {
            int m = mw + g * 4 + r;
            idx[m] = i1a[r];
            if (stage0) idx_sum[m] = i1a[r];
            else        idx_sum[m] += i1a[r] * cumprod;
            mind[m] = b1a[r];
            lsum += (double)b1a[r];
            if (b2a[r] - b1a[r] < DELTA) {
                if (b3a[r] - b1a[r] < DELTA) {
                    int slot = atomicAdd(cntF, 1);
                    fullList[slot] = m;
                } else {
                    int slot = atomicAdd(cnt, 1);
                    flagged[slot] = m;
                    cand2[m] = i2a[r];
                }
            }
            int m2 = mw + 16 + g * 4 + r;
            idx[m2] = i1b[r];
            if (stage0) idx_sum[m2] = i1b[r];
            else        idx_sum[m2] += i1b[r] * cumprod;
            mind[m2] = b1b[r];
            lsum += (double)b1b[r];
            if (b2b[r] - b1b[r] < DELTA) {
                if (b3b[r] - b1b[r] < DELTA) {
                    int slot = atomicAdd(cntF, 1);
                    fullList[slot] = m2;
                } else {
                    int slot = atomicAdd(cnt, 1);
                    flagged[slot] = m2;
                    cand2[m2] = i2b[r];
                }
            }
        }
        loss_s[w * 4 + g] = lsum;
    }
    __syncthreads();
    if (tid == 0) {
        double s = 0.0;
        #pragma unroll
        for (int q = 0; q < 16; ++q) s += loss_s[q];
        atomicAdd(loss_acc, s);
    }
}

// ---------------- exact fp64 pair rescan, batched 8 tokens/block ----------------
__global__ __launch_bounds__(256) void rescan_pair_k(const float* __restrict__ z,
                                                     const float* __restrict__ zqv,
                                                     const float* __restrict__ WinT,
                                                     const float* __restrict__ cb,
                                                     const double* __restrict__ vnorm64,
                                                     const int* __restrict__ flagged,
                                                     const int* __restrict__ cnt,
                                                     const int* __restrict__ cand2,
                                                     int* __restrict__ idx,
                                                     int* __restrict__ idx_sum,
                                                     float* __restrict__ mind,
                                                     double* __restrict__ loss_acc,
                                                     int cumprod, int stage0) {
    __shared__ double r64[8][CIN];           // 32 KB; first 16 KB reused as zi64[8][256]
    __shared__ int mArr[8], cAArr[8], cBArr[8];
    double* zi_l = &r64[0][0];               // alias (used after sync)
    const int tid = threadIdx.x;
    const int w = tid >> 6, l = tid & 63;
    const int n = *cnt;

    for (int jb = blockIdx.x; jb * 8 < n; jb += gridDim.x) {
        const int nt = min(8, n - jb * 8);
        __syncthreads();                     // protect LDS reuse across jb
        if (tid < nt) {
            int m = flagged[jb * 8 + tid];
            mArr[tid] = m;
            cAArr[tid] = idx[m]; cBArr[tid] = cand2[m];
        }
        __syncthreads();
        // stage residuals (coalesced): thread covers k = tid, tid+256
        for (int t = 0; t < nt; ++t) {
            const int m = mArr[t];
            #pragma unroll
            for (int h = 0; h < 2; ++h) {
                int k = tid + h * 256;
                float rv = z[(size_t)m * CIN + k];
                if (!stage0) rv -= zqv[(size_t)m * CIN + k];   // fp32 subtract (matches ref)
                r64[t][k] = (double)rv;
            }
        }
        __syncthreads();
        // zi64: thread e = tid computes 8 dots; WinT rows read coalesced, r64 broadcast
        double acc[8] = {0, 0, 0, 0, 0, 0, 0, 0};
        #pragma unroll 4
        for (int k = 0; k < CIN; ++k) {
            double wv = (double)WinT[(size_t)k * EMB + tid];
            #pragma unroll
            for (int t = 0; t < 8; ++t) acc[t] += r64[t][k] * wv;
        }
        __syncthreads();
        #pragma unroll
        for (int t = 0; t < 8; ++t) zi_l[t * 256 + tid] = acc[t];
        __syncthreads();

        // wave w handles tokens t = w, w+4
        for (int t = w; t < nt; t += 4) {
            const int cA = cAArr[t], cB = cBArr[t], m = mArr[t];
            const double* zt = zi_l + t * 256;
            float4 vA = *(const float4*)(cb + (size_t)cA * EMB + 4 * l);
            float4 vB = *(const float4*)(cb + (size_t)cB * EMB + 4 * l);
            double z0 = zt[4 * l], z1 = zt[4 * l + 1];
            double z2 = zt[4 * l + 2], z3 = zt[4 * l + 3];
            double sA = z0 * (double)vA.x + z1 * (double)vA.y
                      + z2 * (double)vA.z + z3 * (double)vA.w;
            double sB = z0 * (double)vB.x + z1 * (double)vB.y
                      + z2 * (double)vB.z + z3 * (double)vB.w;
            #pragma unroll
            for (int off = 1; off < 64; off <<= 1) {
                sA += __shfl_xor(sA, off, 64);
                sB += __shfl_xor(sB, off, 64);
            }
            if (l == 0) {
                double dA = vnorm64[cA] - 2.0 * sA;
                double dB = vnorm64[cB] - 2.0 * sB;
                int bi; double best;
                if (dB < dA || (dB == dA && cB < cA)) { bi = cB; best = dB; }
                else                                   { bi = cA; best = dA; }
                int oldI = idx[m];
                if (bi != oldI) { idx[m] = bi; idx_sum[m] += (bi - oldI) * cumprod; }
                atomicAdd(loss_acc, best - (double)mind[m]);
                mind[m] = (float)best;
            }
        }
    }
}

// ---------------- exact fp64 full scan, one block per full token, thread-per-code ----------------
__global__ __launch_bounds__(256) void fullscan_k(const float* __restrict__ z,
                                                  const float* __restrict__ zqv,
                                                  const float* __restrict__ WinT,
                                                  const float* __restrict__ cb,
                                                  const double* __restrict__ vnorm64,
                                                  const int* __restrict__ fullList,
                                                  const int* __restrict__ cntF,
                                                  int* __restrict__ idx,
                                                  int* __restrict__ idx_sum,
                                                  float* __restrict__ mind,
                                                  double* __restrict__ loss_acc,
                                                  int cumprod, int stage0) {
    __shared__ double r64[CIN];
    __shared__ double zi64[EMB];
    __shared__ double sred[256];
    __shared__ int ired[256];
    const int tid = threadIdx.x;
    const int n = *cntF;

    for (int j = blockIdx.x; j < n; j += gridDim.x) {
        const int m = fullList[j];
        __syncthreads();                     // protect LDS reuse across j
        #pragma unroll
        for (int h = 0; h < 2; ++h) {
            int k = tid + h * 256;
            float rv = z[(size_t)m * CIN + k];
            if (!stage0) rv -= zqv[(size_t)m * CIN + k];
            r64[k] = (double)rv;
        }
        __syncthreads();
        {
            double acc = 0.0;
            #pragma unroll 8
            for (int k = 0; k < CIN; ++k)
                acc += r64[k] * (double)WinT[(size_t)k * EMB + tid];
            zi64[tid] = acc;
        }
        __syncthreads();
        // thread t scores codes {t, 256+t, 512+t, 768+t} (ascending per thread)
        double best = 1e300; int bi = 0;
        #pragma unroll
        for (int q = 0; q < 4; ++q) {
            const int c = q * 256 + tid;
            const float* row = cb + (size_t)c * EMB;
            double s0 = 0, s1 = 0, s2 = 0, s3 = 0;
            #pragma unroll 4
            for (int e = 0; e < EMB; e += 4) {
                float4 v = *(const float4*)(row + e);
                s0 += zi64[e]     * (double)v.x;
                s1 += zi64[e + 1] * (double)v.y;
                s2 += zi64[e + 2] * (double)v.z;
                s3 += zi64[e + 3] * (double)v.w;
            }
            double sc = vnorm64[c] - 2.0 * ((s0 + s1) + (s2 + s3));
            if (sc < best) { best = sc; bi = c; }
        }
        sred[tid] = best; ired[tid] = bi;
        __syncthreads();
        for (int off = 128; off > 0; off >>= 1) {
            if (tid < off) {
                double ob = sred[tid + off]; int oi = ired[tid + off];
                if (ob < sred[tid] || (ob == sred[tid] && oi < ired[tid])) {
                    sred[tid] = ob; ired[tid] = oi;
                }
            }
            __syncthreads();
        }
        if (tid == 0) {
            int oldI = idx[m], bi2 = ired[0];
            double best2 = sred[0];
            if (bi2 != oldI) { idx[m] = bi2; idx_sum[m] += (bi2 - oldI) * cumprod; }
            atomicAdd(loss_acc, best2 - (double)mind[m]);
            mind[m] = (float)best2;
        }
    }
}

// ---------------- zq (+)= T[idx]  (row gather); last stage also sums (z - zq)^2 ----------------
__global__ __launch_bounds__(256) void gather_k(const float* __restrict__ T,
                                                const int* __restrict__ idx,
                                                const float* __restrict__ z,
                                                float* __restrict__ zq,
                                                int stage0, int last,
                                                double* __restrict__ loss_acc) {
    __shared__ double red[256];
    int m = blockIdx.x * 16 + (threadIdx.x >> 4);
    int q = threadIdx.x & 15;
    const float* src = T + (size_t)idx[m] * CIN;
    float* dst = zq + (size_t)m * CIN;
    double s = 0.0;
    #pragma unroll
    for (int it = 0; it < 8; ++it) {
        int off = it * 64 + q * 4;
        float4 t = *reinterpret_cast<const float4*>(src + off);
        if (!stage0) {
            float4 o = *reinterpret_cast<const float4*>(dst + off);
            t.x += o.x; t.y += o.y; t.z += o.z; t.w += o.w;
        }
        *reinterpret_cast<float4*>(dst + off) = t;
        if (last) {
            float4 zv = *reinterpret_cast<const float4*>(z + (size_t)m * CIN + off);
            double d0 = (double)zv.x - (double)t.x;
            double d1 = (double)zv.y - (double)t.y;
            double d2 = (double)zv.z - (double)t.z;
            double d3 = (double)zv.w - (double)t.w;
            s += d0 * d0 + d1 * d1 + d2 * d2 + d3 * d3;
        }
    }
    if (last) {
        red[threadIdx.x] = s;
        __syncthreads();
        for (int off = 128; off > 0; off >>= 1) {
            if (threadIdx.x < off) red[threadIdx.x] += red[threadIdx.x + off];
            __syncthreads();
        }
        if (threadIdx.x == 0) atomicAdd(loss_acc + 1, red[0]);
    }
}

// ---------------- finalize ----------------
__global__ void final_k(const int* __restrict__ idx_sum,
                        const double* __restrict__ loss_acc,
                        float* __restrict__ out) {
    int i = blockIdx.x * blockDim.x + threadIdx.x;
    if (i < MTOK) out[MTOK * CIN + i] = (float)idx_sum[i];
    if (i == 0) {
        double loss = 2.0 * loss_acc[0] / (3.0 * (double)MTOK * (double)EMB)
                    + loss_acc[1] / ((double)MTOK * (double)CIN);
        out[MTOK * CIN + MTOK] = (float)loss;
    }
}

extern "C" void kernel_launch(void* const* d_in, const int* in_sizes, int n_in,
                              void* d_out, int out_size, void* d_ws, size_t ws_size,
                              hipStream_t stream) {
    const float* z     = (const float*)d_in[0];
    const float* W_in  = (const float*)d_in[1];
    const float* W_out = (const float*)d_in[2];
    const float* cbs   = (const float*)d_in[3];
    float* out = (float*)d_out;
    char* ws = (char*)d_ws;

    // ws layout (16B-aligned)
    double* vnorm64  = (double*)ws;                               // 24576
    double* loss_acc = (double*)(ws + 24576);                     // 16
    int*    cnt      = (int*)(ws + 24592);                        // 32 ([0..2] pair, [3..5] full)
    float*  vnorm32  = (float*)(ws + 24624);                      // 12288 -> 36912
    u16*    cbh      = (u16*)(ws + 36912);                        // 1572864 -> 1609776
    u16*    cbl      = (u16*)(ws + 1609776);                      // 1572864 -> 3182640
    u16*    wh       = (u16*)(ws + 3182640);                      // 786432 -> 3969072
    u16*    wl       = (u16*)(ws + 3969072);                      // 786432 -> 4755504
    float*  WinT     = (float*)(ws + 4755504);                    // 1572864 -> 6328368
    float*  T        = (float*)(ws + 6328368);                    // 6291456 -> 12619824
    float*  zi       = (float*)(ws + 12619824);                   // 33554432 -> 46174256
    char*   p        = ws + 46174256;
    int*    idx      = (int*)p;                                   // 131072
    int*    idx_sum  = (int*)(p + 131072);                        // 131072
    int*    flagged  = (int*)(p + 262144);                        // 131072
    float*  mind     = (float*)(p + 393216);                      // 131072
    int*    cand2    = (int*)(p + 524288);                        // 131072
    int*    fullList = (int*)(p + 655360);                        // 131072

    float* zq = out;  // z_q lives in d_out[0 .. MTOK*CIN)

    init_k<<<dim3(1), dim3(1), 0, stream>>>(loss_acc, cnt);
    prep_cb_k<<<dim3(VQ * NCODE), dim3(64), 0, stream>>>(cbs, vnorm64, vnorm32, cbh, cbl);
    prep_w_k<<<dim3(VQ * EMB * CIN / 256), dim3(256), 0, stream>>>(W_in, wh, wl);
    prep_wt_k<<<dim3(VQ * EMB * CIN / 256), dim3(256), 0, stream>>>(W_in, WinT);
    prep_T_k<<<dim3(NCODE / 64, CIN / 64, VQ), dim3(256), 0, stream>>>(cbs, W_out, T);

    const int cumprod[VQ] = {1, 1024, 1024 * 1024};
    for (int i = 0; i < VQ; ++i) {
        const float* cb = cbs + (size_t)i * NCODE * EMB;
        zi_mfma_k<<<dim3(MTOK / 64), dim3(256), 0, stream>>>(
            z, zq, wh + (size_t)i * EMB * CIN, wl + (size_t)i * EMB * CIN,
            zi, loss_acc, i == 0 ? 1 : 0);
        pref_k<<<dim3(MTOK / 128), dim3(256), 0, stream>>>(
            zi, cbh + (size_t)i * NCODE * EMB, cbl + (size_t)i * NCODE * EMB,
            vnorm32 + i * NCODE, idx, idx_sum, mind, flagged, cnt + i,
            fullList, cnt + 3 + i, cand2, loss_acc, i == 0 ? 1 : 0, cumprod[i]);
        rescan_pair_k<<<dim3(512), dim3(256), 0, stream>>>(
            z, zq, WinT + (size_t)i * EMB * CIN, cb, vnorm64 + i * NCODE,
            flagged, cnt + i, cand2, idx, idx_sum, mind, loss_acc, cumprod[i],
            i == 0 ? 1 : 0);
        fullscan_k<<<dim3(256), dim3(256), 0, stream>>>(
            z, zq, WinT + (size_t)i * EMB * CIN, cb, vnorm64 + i * NCODE,
            fullList, cnt + 3 + i, idx, idx_sum, mind, loss_acc, cumprod[i],
            i == 0 ? 1 : 0);
        gather_k<<<dim3(MTOK / 16), dim3(256), 0, stream>>>(
            T + (size_t)i * NCODE * CIN, idx, z, zq, i == 0 ? 1 : 0,
            i == VQ - 1 ? 1 : 0, loss_acc);
    }
    final_k<<<dim3(MTOK / 256), dim3(256), 0, stream>>>(idx_sum, loss_acc, out);
}

// Round 12
// 989.473 us; speedup vs baseline: 1.0385x; 1.0385x over previous
//
#include <hip/hip_runtime.h>

#define MTOK 32768   // 8*4096 tokens
#define CIN  512     // in_ch
#define EMB  256     // emb_ch
#define NCODE 1024
#define VQ   3
#define DELTA 2e-3f  // certified margin; worst-case approx score-diff error ~3e-4

typedef short s16x8 __attribute__((ext_vector_type(8)));
typedef float f32x4 __attribute__((ext_vector_type(4)));
typedef unsigned short u16;

static __device__ __forceinline__ u16 f2bf(float x) {
    unsigned int u = __float_as_uint(x);
    u += 0x7FFF + ((u >> 16) & 1);          // RNE
    return (u16)(u >> 16);
}
static __device__ __forceinline__ float bf2f(u16 h) {
    return __uint_as_float(((unsigned int)h) << 16);
}

// ---------------- init ----------------
__global__ void init_k(double* loss_acc, int* cnt) {
    loss_acc[0] = 0.0;  // sum of min-dists (znorm parts + score parts)
    loss_acc[1] = 0.0;  // sum (z - z_q)^2
    #pragma unroll
    for (int i = 0; i < 8; ++i) cnt[i] = 0;   // [0..2]=pair counts, [3..5]=full counts
}

// ---------------- codebook prep: ||v||^2 (fp64/fp32) + bf16 hi/lo split ----------------
__global__ __launch_bounds__(64) void prep_cb_k(const float* __restrict__ cbs,
                                                double* __restrict__ vnorm64,
                                                float* __restrict__ vnorm32,
                                                u16* __restrict__ cbh,
                                                u16* __restrict__ cbl) {
    int s = blockIdx.x;                       // 0 .. 3*NCODE-1
    const float* row = cbs + (size_t)s * EMB;
    double acc = 0.0;
    for (int k = threadIdx.x; k < EMB; k += 64) {
        float v = row[k];
        double vd = (double)v; acc += vd * vd;
        u16 h = f2bf(v);
        u16 l = f2bf(v - bf2f(h));
        cbh[(size_t)s * EMB + k] = h;
        cbl[(size_t)s * EMB + k] = l;
    }
    #pragma unroll
    for (int off = 32; off > 0; off >>= 1) acc += __shfl_down(acc, off, 64);
    if (threadIdx.x == 0) { vnorm64[s] = acc; vnorm32[s] = (float)acc; }
}

// ---------------- W_in bf16 hi/lo split ----------------
__global__ __launch_bounds__(256) void prep_w_k(const float* __restrict__ W_in,
                                                u16* __restrict__ wh,
                                                u16* __restrict__ wl) {
    int i = blockIdx.x * 256 + threadIdx.x;   // < VQ*EMB*CIN
    float v = W_in[i];
    u16 h = f2bf(v);
    wh[i] = h;
    wl[i] = f2bf(v - bf2f(h));
}

// ---------------- W_in transpose: WinT[s][k][e] = W_in[s][e][k] (exact fp32) ----------------
__global__ __launch_bounds__(256) void prep_wt_k(const float* __restrict__ W_in,
                                                 float* __restrict__ WinT) {
    int i = blockIdx.x * 256 + threadIdx.x;   // < VQ*EMB*CIN
    int s = i / (EMB * CIN);
    int rem = i - s * (EMB * CIN);
    int e = rem / CIN;
    int k = rem - e * CIN;
    WinT[(size_t)s * CIN * EMB + (size_t)k * EMB + e] = W_in[i];
}

// ---------------- T[s] = cb[s] @ W_out[s]^T  (fp64 acc, fp32 store) ----------------
__global__ __launch_bounds__(256) void prep_T_k(const float* __restrict__ cbs,
                                                const float* __restrict__ Wout,
                                                float* __restrict__ T) {
    const int stage = blockIdx.z;
    const float* A = cbs  + (size_t)stage * NCODE * EMB;
    const float* B = Wout + (size_t)stage * CIN * EMB;
    float* C = T + (size_t)stage * NCODE * CIN;
    __shared__ float As[64][33];
    __shared__ float Bs[64][33];
    const int tid = threadIdx.x;
    const int ty = tid >> 4, tx = tid & 15;
    const int m0 = blockIdx.x * 64;
    const int n0 = blockIdx.y * 64;
    const int lrow = tid >> 5, lcol = tid & 31;
    double acc[4][4];
    #pragma unroll
    for (int i = 0; i < 4; ++i)
        #pragma unroll
        for (int j = 0; j < 4; ++j) acc[i][j] = 0.0;

    for (int k0 = 0; k0 < EMB; k0 += 32) {
        __syncthreads();
        #pragma unroll
        for (int t = 0; t < 8; ++t) {
            int r = lrow + 8 * t;
            As[r][lcol] = A[(size_t)(m0 + r) * EMB + k0 + lcol];
            Bs[r][lcol] = B[(size_t)(n0 + r) * EMB + k0 + lcol];
        }
        __syncthreads();
        #pragma unroll
        for (int k = 0; k < 32; ++k) {
            double a[4], b[4];
            #pragma unroll
            for (int i = 0; i < 4; ++i) a[i] = (double)As[ty * 4 + i][k];
            #pragma unroll
            for (int j = 0; j < 4; ++j) b[j] = (double)Bs[tx * 4 + j][k];
            #pragma unroll
            for (int i = 0; i < 4; ++i)
                #pragma unroll
                for (int j = 0; j < 4; ++j) acc[i][j] += a[i] * b[j];
        }
    }
    #pragma unroll
    for (int i = 0; i < 4; ++i) {
        float4 v = make_float4((float)acc[i][0], (float)acc[i][1],
                               (float)acc[i][2], (float)acc[i][3]);
        *reinterpret_cast<float4*>(&C[(size_t)(m0 + ty * 4 + i) * CIN + n0 + tx * 4]) = v;
    }
}

// ---------------- zi = (z - zq) @ W_in^T via bf16-split MFMA, dbuf LDS W ----------------
__global__ __launch_bounds__(256, 2) void zi_mfma_k(const float* __restrict__ z,
                                                    const float* __restrict__ zq,
                                                    const u16* __restrict__ wh,
                                                    const u16* __restrict__ wl,
                                                    float* __restrict__ zi,
                                                    double* __restrict__ loss_acc,
                                                    int stage0) {
    __shared__ __align__(16) u16 swh[2][16][520];
    __shared__ __align__(16) u16 swl[2][16][520];
    const int tid = threadIdx.x;
    const int w = tid >> 6;
    const int l = tid & 63;
    const int col = l & 15;
    const int g = l >> 4;
    const int mw = blockIdx.x * 64 + w * 16;
    const int sr = tid >> 4, sq = tid & 15;

    // A fragments: bf16 hi/lo split of residual row (mw+col), k = kc*32 + g*8 + j
    s16x8 ah[16], al[16];
    {
        const float* zr = z  + (size_t)(mw + col) * CIN + g * 8;
        const float* qr = zq + (size_t)(mw + col) * CIN + g * 8;
        #pragma unroll
        for (int kc = 0; kc < 16; ++kc) {
            float4 f0 = *reinterpret_cast<const float4*>(zr + kc * 32);
            float4 f1 = *reinterpret_cast<const float4*>(zr + kc * 32 + 4);
            float f[8] = {f0.x, f0.y, f0.z, f0.w, f1.x, f1.y, f1.z, f1.w};
            if (!stage0) {
                float4 q0 = *reinterpret_cast<const float4*>(qr + kc * 32);
                float4 q1 = *reinterpret_cast<const float4*>(qr + kc * 32 + 4);
                f[0] -= q0.x; f[1] -= q0.y; f[2] -= q0.z; f[3] -= q0.w;
                f[4] -= q1.x; f[5] -= q1.y; f[6] -= q1.z; f[7] -= q1.w;
            }
            #pragma unroll
            for (int j = 0; j < 8; ++j) {
                u16 h = f2bf(f[j]);
                u16 lo = f2bf(f[j] - bf2f(h));
                ah[kc][j] = (short)h; al[kc][j] = (short)lo;
            }
        }
    }

    const u16* gh = wh + (size_t)sr * CIN + sq * 8;
    const u16* gl = wl + (size_t)sr * CIN + sq * 8;
    uint4 h0, h1, h2, h3, l0, l1, l2, l3;
#define ZLOAD(NT) do { const u16* th = gh + (size_t)(NT) * (16 * CIN);                \
    const u16* tl = gl + (size_t)(NT) * (16 * CIN);                                   \
    h0 = *(const uint4*)(th);        h1 = *(const uint4*)(th + 128);                  \
    h2 = *(const uint4*)(th + 256);  h3 = *(const uint4*)(th + 384);                  \
    l0 = *(const uint4*)(tl);        l1 = *(const uint4*)(tl + 128);                  \
    l2 = *(const uint4*)(tl + 256);  l3 = *(const uint4*)(tl + 384); } while (0)
#define ZWRITE(P) do {                                                                \
    *(uint4*)&swh[P][sr][sq * 8]       = h0;  *(uint4*)&swh[P][sr][sq * 8 + 128] = h1;\
    *(uint4*)&swh[P][sr][sq * 8 + 256] = h2;  *(uint4*)&swh[P][sr][sq * 8 + 384] = h3;\
    *(uint4*)&swl[P][sr][sq * 8]       = l0;  *(uint4*)&swl[P][sr][sq * 8 + 128] = l1;\
    *(uint4*)&swl[P][sr][sq * 8 + 256] = l2;  *(uint4*)&swl[P][sr][sq * 8 + 384] = l3;\
    } while (0)
    ZLOAD(0); ZWRITE(0); ZLOAD(1);

    double zn = 0.0;
    for (int nt = 0; nt < 16; ++nt) {
        __syncthreads();                         // buf[nt&1] ready; prev reads done
        const int p = nt & 1;
        if (nt + 1 < 16) ZWRITE((nt + 1) & 1);
        if (nt + 2 < 16) ZLOAD(nt + 2);
        f32x4 a0 = {0.f, 0.f, 0.f, 0.f};
        f32x4 a1 = {0.f, 0.f, 0.f, 0.f};
        f32x4 a2 = {0.f, 0.f, 0.f, 0.f};
        #pragma unroll
        for (int kc = 0; kc < 16; ++kc) {
            s16x8 Bh = *(const s16x8*)&swh[p][col][g * 8 + kc * 32];
            s16x8 Bl = *(const s16x8*)&swl[p][col][g * 8 + kc * 32];
            a0 = __builtin_amdgcn_mfma_f32_16x16x32_bf16(ah[kc], Bh, a0, 0, 0, 0);
            a1 = __builtin_amdgcn_mfma_f32_16x16x32_bf16(al[kc], Bh, a1, 0, 0, 0);
            a2 = __builtin_amdgcn_mfma_f32_16x16x32_bf16(ah[kc], Bl, a2, 0, 0, 0);
        }
        #pragma unroll
        for (int r = 0; r < 4; ++r) {
            float v = a0[r] + a1[r] + a2[r];
            zi[(size_t)(mw + g * 4 + r) * EMB + nt * 16 + col] = v;
            zn += (double)v * (double)v;
        }
    }
#undef ZLOAD
#undef ZWRITE
    #pragma unroll
    for (int off = 32; off > 0; off >>= 1) zn += __shfl_down(zn, off, 64);
    if (l == 0) atomicAdd(loss_acc, zn);
}

// ---------------- MFMA bf16-split prefilter: 32 tok/wave, half-codebook/block ----------------
// Block = 4 waves x 32 tokens = 128 tokens over 512 codes (blockIdx.y = half).
// Emits per-token partial top-3 (scores + top-2 indices); merge_k combines halves.
__global__ __launch_bounds__(256, 2) void pref_k(const float* __restrict__ zi,
                                                 const u16* __restrict__ cbh,
                                                 const u16* __restrict__ cbl,
                                                 const float* __restrict__ vnorm32,
                                                 float* __restrict__ pb1,
                                                 float* __restrict__ pb2,
                                                 float* __restrict__ pb3,
                                                 int* __restrict__ pi1,
                                                 int* __restrict__ pi2) {
    __shared__ __align__(16) u16 sbh[2][16][264];
    __shared__ __align__(16) u16 sbl[2][16][264];
    const int tid = threadIdx.x;
    const int w = tid >> 6;
    const int l = tid & 63;
    const int col = l & 15;
    const int g = l >> 4;
    const int mw = blockIdx.x * 128 + w * 32;    // 32 tokens per wave
    const int half = blockIdx.y;
    const int ct0 = half * 32;                   // 32 ct-tiles = 512 codes
    const int sr = tid >> 4, sq = tid & 15;

    s16x8 ah0[8], al0[8], ah1[8], al1[8];
    {
        const float* zr0 = zi + (size_t)(mw + col) * EMB + g * 8;
        const float* zr1 = zi + (size_t)(mw + 16 + col) * EMB + g * 8;
        #pragma unroll
        for (int kc = 0; kc < 8; ++kc) {
            float4 f0 = *reinterpret_cast<const float4*>(zr0 + kc * 32);
            float4 f1 = *reinterpret_cast<const float4*>(zr0 + kc * 32 + 4);
            float f[8] = {f0.x, f0.y, f0.z, f0.w, f1.x, f1.y, f1.z, f1.w};
            #pragma unroll
            for (int j = 0; j < 8; ++j) {
                u16 h = f2bf(f[j]);
                u16 lo = f2bf(f[j] - bf2f(h));
                ah0[kc][j] = (short)h;
                al0[kc][j] = (short)lo;
            }
            float4 e0 = *reinterpret_cast<const float4*>(zr1 + kc * 32);
            float4 e1 = *reinterpret_cast<const float4*>(zr1 + kc * 32 + 4);
            float e[8] = {e0.x, e0.y, e0.z, e0.w, e1.x, e1.y, e1.z, e1.w};
            #pragma unroll
            for (int j = 0; j < 8; ++j) {
                u16 h = f2bf(e[j]);
                u16 lo = f2bf(e[j] - bf2f(h));
                ah1[kc][j] = (short)h;
                al1[kc][j] = (short)lo;
            }
        }
    }

    float b1a[4], b2a[4], b3a[4], b1b[4], b2b[4], b3b[4];
    int   i1a[4], i2a[4], i1b[4], i2b[4];
    #pragma unroll
    for (int r = 0; r < 4; ++r) {
        b1a[r] = b2a[r] = b3a[r] = 1e30f; i1a[r] = i2a[r] = 0;
        b1b[r] = b2b[r] = b3b[r] = 1e30f; i1b[r] = i2b[r] = 0;
    }

    const u16* gh = cbh + (size_t)sr * EMB + sq * 8;
    const u16* gl = cbl + (size_t)sr * EMB + sq * 8;
    uint4 h0, h1, l0, l1;
#define PLOAD(CT) do { const u16* th = gh + (size_t)(CT) * (16 * EMB);                \
    const u16* tl = gl + (size_t)(CT) * (16 * EMB);                                   \
    h0 = *(const uint4*)(th);  h1 = *(const uint4*)(th + 128);                        \
    l0 = *(const uint4*)(tl);  l1 = *(const uint4*)(tl + 128); } while (0)
#define PWRITE(P) do {                                                                \
    *(uint4*)&sbh[P][sr][sq * 8] = h0;  *(uint4*)&sbh[P][sr][sq * 8 + 128] = h1;      \
    *(uint4*)&sbl[P][sr][sq * 8] = l0;  *(uint4*)&sbl[P][sr][sq * 8 + 128] = l1;      \
    } while (0)
    PLOAD(ct0); PWRITE(0); PLOAD(ct0 + 1);

    for (int ct = ct0; ct < ct0 + 32; ++ct) {
        __syncthreads();                         // buf[ct&1] ready; prev reads done
        const int p = ct & 1;
        if (ct + 1 < ct0 + 32) PWRITE((ct + 1) & 1);
        if (ct + 2 < ct0 + 32) PLOAD(ct + 2);
        const float vn = vnorm32[ct * 16 + col];
        f32x4 a00 = {0.f, 0.f, 0.f, 0.f}, a01 = {0.f, 0.f, 0.f, 0.f}, a02 = {0.f, 0.f, 0.f, 0.f};
        f32x4 a10 = {0.f, 0.f, 0.f, 0.f}, a11 = {0.f, 0.f, 0.f, 0.f}, a12 = {0.f, 0.f, 0.f, 0.f};
        #pragma unroll
        for (int kc = 0; kc < 8; ++kc) {
            s16x8 Bh = *(const s16x8*)&sbh[p][col][g * 8 + kc * 32];
            s16x8 Bl = *(const s16x8*)&sbl[p][col][g * 8 + kc * 32];
            a00 = __builtin_amdgcn_mfma_f32_16x16x32_bf16(ah0[kc], Bh, a00, 0, 0, 0);
            a10 = __builtin_amdgcn_mfma_f32_16x16x32_bf16(ah1[kc], Bh, a10, 0, 0, 0);
            a01 = __builtin_amdgcn_mfma_f32_16x16x32_bf16(al0[kc], Bh, a01, 0, 0, 0);
            a11 = __builtin_amdgcn_mfma_f32_16x16x32_bf16(al1[kc], Bh, a11, 0, 0, 0);
            a02 = __builtin_amdgcn_mfma_f32_16x16x32_bf16(ah0[kc], Bl, a02, 0, 0, 0);
            a12 = __builtin_amdgcn_mfma_f32_16x16x32_bf16(ah1[kc], Bl, a12, 0, 0, 0);
        }
        #pragma unroll
        for (int r = 0; r < 4; ++r) {
            int c = ct * 16 + col;
            float sa = vn - 2.f * (a00[r] + a01[r] + a02[r]);
            if (sa < b1a[r]) { b3a[r] = b2a[r]; b2a[r] = b1a[r]; i2a[r] = i1a[r]; b1a[r] = sa; i1a[r] = c; }
            else if (sa < b2a[r]) { b3a[r] = b2a[r]; b2a[r] = sa; i2a[r] = c; }
            else b3a[r] = fminf(b3a[r], sa);
            float sb = vn - 2.f * (a10[r] + a11[r] + a12[r]);
            if (sb < b1b[r]) { b3b[r] = b2b[r]; b2b[r] = b1b[r]; i2b[r] = i1b[r]; b1b[r] = sb; i1b[r] = c; }
            else if (sb < b2b[r]) { b3b[r] = b2b[r]; b2b[r] = sb; i2b[r] = c; }
            else b3b[r] = fminf(b3b[r], sb);
        }
    }
#undef PLOAD
#undef PWRITE

    // cross-lane top-3 merge over the 16 lanes of each token group (both sets)
#define MERGE16(B1, B2, B3, I1, I2) do {                                              \
    _Pragma("unroll")                                                                 \
    for (int off = 1; off < 16; off <<= 1) {                                          \
        _Pragma("unroll")                                                             \
        for (int r = 0; r < 4; ++r) {                                                 \
            float c1 = __shfl_xor(B1[r], off, 64);                                    \
            int   j1 = __shfl_xor(I1[r], off, 64);                                    \
            float c2 = __shfl_xor(B2[r], off, 64);                                    \
            int   j2 = __shfl_xor(I2[r], off, 64);                                    \
            float c3 = __shfl_xor(B3[r], off, 64);                                    \
            float nb1, nb2, nb3; int ni1, ni2;                                        \
            if (c1 < B1[r] || (c1 == B1[r] && j1 < I1[r])) {                          \
                nb1 = c1; ni1 = j1;                                                   \
                if (B1[r] < c2 || (B1[r] == c2 && I1[r] < j2)) {                      \
                    nb2 = B1[r]; ni2 = I1[r]; nb3 = fminf(B2[r], c2);                 \
                } else {                                                              \
                    nb2 = c2; ni2 = j2; nb3 = fminf(B1[r], c3);                       \
                }                                                                     \
            } else {                                                                  \
                nb1 = B1[r]; ni1 = I1[r];                                             \
                if (c1 < B2[r] || (c1 == B2[r] && j1 < I2[r])) {                      \
                    nb2 = c1; ni2 = j1; nb3 = fminf(B2[r], c2);                       \
                } else {                                                              \
                    nb2 = B2[r]; ni2 = I2[r]; nb3 = fminf(c1, B3[r]);                 \
                }                                                                     \
            }                                                                         \
            B1[r] = nb1; B2[r] = nb2; B3[r] = nb3; I1[r] = ni1; I2[r] = ni2;          \
        }                                                                             \
    }                                                                                 \
} while (0)
    MERGE16(b1a, b2a, b3a, i1a, i2a);
    MERGE16(b1b, b2b, b3b, i1b, i2b);
#undef MERGE16

    if (col == 0) {
        const size_t base = (size_t)half * MTOK;
        #pragma unroll
        for (int r = 0; r < 4; ++r) {
            size_t o = base + mw + g * 4 + r;
            pb1[o] = b1a[r]; pb2[o] = b2a[r]; pb3[o] = b3a[r];
            pi1[o] = i1a[r]; pi2[o] = i2a[r];
            size_t o2 = base + mw + 16 + g * 4 + r;
            pb1[o2] = b1b[r]; pb2[o2] = b2b[r]; pb3[o2] = b3b[r];
            pi1[o2] = i1b[r]; pi2[o2] = i2b[r];
        }
    }
}

// ---------------- merge halves: final top-3, idx/mind/loss, pair/full classify ----------------
__global__ __launch_bounds__(256) void merge_k(const float* __restrict__ pb1,
                                               const float* __restrict__ pb2,
                                               const float* __restrict__ pb3,
                                               const int* __restrict__ pi1,
                                               const int* __restrict__ pi2,
                                               int* __restrict__ idx,
                                               int* __restrict__ idx_sum,
                                               float* __restrict__ mind,
                                               int* __restrict__ flagged,
                                               int* __restrict__ cnt,
                                               int* __restrict__ fullList,
                                               int* __restrict__ cntF,
                                               int* __restrict__ cand2,
                                               double* __restrict__ loss_acc,
                                               int stage0, int cumprod) {
    __shared__ double red[256];
    const int m = blockIdx.x * 256 + threadIdx.x;
    float a1 = pb1[m], a2 = pb2[m], a3 = pb3[m];
    int   ja1 = pi1[m], ja2 = pi2[m];
    float e1 = pb1[MTOK + m], e2 = pb2[MTOK + m], e3 = pb3[MTOK + m];
    int   je1 = pi1[MTOK + m], je2 = pi2[MTOK + m];

    // merge two internally-sorted top-3 lists; 3rd slot is score-only
    bool aF = (a1 < e1) || (a1 == e1 && ja1 < je1);
    float m1 = aF ? a1 : e1;  int j1 = aF ? ja1 : je1;
    float x  = aF ? a2 : a1;  int jx = aF ? ja2 : ja1;
    float y  = aF ? e1 : e2;  int jy = aF ? je1 : je2;
    bool aF2 = (x < y) || (x == y && jx < jy);
    float m2 = aF2 ? x : y;   int j2 = aF2 ? jx : jy;
    int ta = (aF ? 1 : 0) + (aF2 ? 1 : 0);   // taken from A so far
    float an = (ta == 0) ? a1 : ((ta == 1) ? a2 : a3);
    float en = (ta == 2) ? e1 : ((ta == 1) ? e2 : e3);
    float m3 = fminf(an, en);

    idx[m] = j1;
    if (stage0) idx_sum[m] = j1;
    else        idx_sum[m] += j1 * cumprod;
    mind[m] = m1;
    if (m2 - m1 < DELTA) {
        if (m3 - m1 < DELTA) {
            int slot = atomicAdd(cntF, 1);
            fullList[slot] = m;
        } else {
            int slot = atomicAdd(cnt, 1);
            flagged[slot] = m;
            cand2[m] = j2;
        }
    }
    red[threadIdx.x] = (double)m1;
    __syncthreads();
    for (int off = 128; off > 0; off >>= 1) {
        if (threadIdx.x < off) red[threadIdx.x] += red[threadIdx.x + off];
        __syncthreads();
    }
    if (threadIdx.x == 0) atomicAdd(loss_acc, red[0]);
}

// ---------------- exact fp64 pair rescan, batched 8 tokens/block ----------------
__global__ __launch_bounds__(256) void rescan_pair_k(const float* __restrict__ z,
                                                     const float* __restrict__ zqv,
                                                     const float* __restrict__ WinT,
                                                     const float* __restrict__ cb,
                                                     const double* __restrict__ vnorm64,
                                                     const int* __restrict__ flagged,
                                                     const int* __restrict__ cnt,
                                                     const int* __restrict__ cand2,
                                                     int* __restrict__ idx,
                                                     int* __restrict__ idx_sum,
                                                     float* __restrict__ mind,
                                                     double* __restrict__ loss_acc,
                                                     int cumprod, int stage0) {
    __shared__ double r64[8][CIN];           // 32 KB; first 16 KB reused as zi64[8][256]
    __shared__ int mArr[8], cAArr[8], cBArr[8];
    double* zi_l = &r64[0][0];               // alias (used after sync)
    const int tid = threadIdx.x;
    const int w = tid >> 6, l = tid & 63;
    const int n = *cnt;

    for (int jb = blockIdx.x; jb * 8 < n; jb += gridDim.x) {
        const int nt = min(8, n - jb * 8);
        __syncthreads();                     // protect LDS reuse across jb
        if (tid < nt) {
            int m = flagged[jb * 8 + tid];
            mArr[tid] = m;
            cAArr[tid] = idx[m]; cBArr[tid] = cand2[m];
        }
        __syncthreads();
        // stage residuals (coalesced): thread covers k = tid, tid+256
        for (int t = 0; t < nt; ++t) {
            const int m = mArr[t];
            #pragma unroll
            for (int h = 0; h < 2; ++h) {
                int k = tid + h * 256;
                float rv = z[(size_t)m * CIN + k];
                if (!stage0) rv -= zqv[(size_t)m * CIN + k];   // fp32 subtract (matches ref)
                r64[t][k] = (double)rv;
            }
        }
        __syncthreads();
        // zi64: thread e = tid computes 8 dots; WinT rows read coalesced, r64 broadcast
        double acc[8] = {0, 0, 0, 0, 0, 0, 0, 0};
        #pragma unroll 4
        for (int k = 0; k < CIN; ++k) {
            double wv = (double)WinT[(size_t)k * EMB + tid];
            #pragma unroll
            for (int t = 0; t < 8; ++t) acc[t] += r64[t][k] * wv;
        }
        __syncthreads();
        #pragma unroll
        for (int t = 0; t < 8; ++t) zi_l[t * 256 + tid] = acc[t];
        __syncthreads();

        // wave w handles tokens t = w, w+4
        for (int t = w; t < nt; t += 4) {
            const int cA = cAArr[t], cB = cBArr[t], m = mArr[t];
            const double* zt = zi_l + t * 256;
            float4 vA = *(const float4*)(cb + (size_t)cA * EMB + 4 * l);
            float4 vB = *(const float4*)(cb + (size_t)cB * EMB + 4 * l);
            double z0 = zt[4 * l], z1 = zt[4 * l + 1];
            double z2 = zt[4 * l + 2], z3 = zt[4 * l + 3];
            double sA = z0 * (double)vA.x + z1 * (double)vA.y
                      + z2 * (double)vA.z + z3 * (double)vA.w;
            double sB = z0 * (double)vB.x + z1 * (double)vB.y
                      + z2 * (double)vB.z + z3 * (double)vB.w;
            #pragma unroll
            for (int off = 1; off < 64; off <<= 1) {
                sA += __shfl_xor(sA, off, 64);
                sB += __shfl_xor(sB, off, 64);
            }
            if (l == 0) {
                double dA = vnorm64[cA] - 2.0 * sA;
                double dB = vnorm64[cB] - 2.0 * sB;
                int bi; double best;
                if (dB < dA || (dB == dA && cB < cA)) { bi = cB; best = dB; }
                else                                   { bi = cA; best = dA; }
                int oldI = idx[m];
                if (bi != oldI) { idx[m] = bi; idx_sum[m] += (bi - oldI) * cumprod; }
                atomicAdd(loss_acc, best - (double)mind[m]);
                mind[m] = (float)best;
            }
        }
    }
}

// ---------------- exact fp64 full scan, one block per full token, thread-per-code ----------------
__global__ __launch_bounds__(256) void fullscan_k(const float* __restrict__ z,
                                                  const float* __restrict__ zqv,
                                                  const float* __restrict__ WinT,
                                                  const float* __restrict__ cb,
                                                  const double* __restrict__ vnorm64,
                                                  const int* __restrict__ fullList,
                                                  const int* __restrict__ cntF,
                                                  int* __restrict__ idx,
                                                  int* __restrict__ idx_sum,
                                                  float* __restrict__ mind,
                                                  double* __restrict__ loss_acc,
                                                  int cumprod, int stage0) {
    __shared__ double r64[CIN];
    __shared__ double zi64[EMB];
    __shared__ double sred[256];
    __shared__ int ired[256];
    const int tid = threadIdx.x;
    const int n = *cntF;

    for (int j = blockIdx.x; j < n; j += gridDim.x) {
        const int m = fullList[j];
        __syncthreads();                     // protect LDS reuse across j
        #pragma unroll
        for (int h = 0; h < 2; ++h) {
            int k = tid + h * 256;
            float rv = z[(size_t)m * CIN + k];
            if (!stage0) rv -= zqv[(size_t)m * CIN + k];
            r64[k] = (double)rv;
        }
        __syncthreads();
        {
            double acc = 0.0;
            #pragma unroll 8
            for (int k = 0; k < CIN; ++k)
                acc += r64[k] * (double)WinT[(size_t)k * EMB + tid];
            zi64[tid] = acc;
        }
        __syncthreads();
        // thread t scores codes {t, 256+t, 512+t, 768+t} (ascending per thread)
        double best = 1e300; int bi = 0;
        #pragma unroll
        for (int q = 0; q < 4; ++q) {
            const int c = q * 256 + tid;
            const float* row = cb + (size_t)c * EMB;
            double s0 = 0, s1 = 0, s2 = 0, s3 = 0;
            #pragma unroll 4
            for (int e = 0; e < EMB; e += 4) {
                float4 v = *(const float4*)(row + e);
                s0 += zi64[e]     * (double)v.x;
                s1 += zi64[e + 1] * (double)v.y;
                s2 += zi64[e + 2] * (double)v.z;
                s3 += zi64[e + 3] * (double)v.w;
            }
            double sc = vnorm64[c] - 2.0 * ((s0 + s1) + (s2 + s3));
            if (sc < best) { best = sc; bi = c; }
        }
        sred[tid] = best; ired[tid] = bi;
        __syncthreads();
        for (int off = 128; off > 0; off >>= 1) {
            if (tid < off) {
                double ob = sred[tid + off]; int oi = ired[tid + off];
                if (ob < sred[tid] || (ob == sred[tid] && oi < ired[tid])) {
                    sred[tid] = ob; ired[tid] = oi;
                }
            }
            __syncthreads();
        }
        if (tid == 0) {
            int oldI = idx[m], bi2 = ired[0];
            double best2 = sred[0];
            if (bi2 != oldI) { idx[m] = bi2; idx_sum[m] += (bi2 - oldI) * cumprod; }
            atomicAdd(loss_acc, best2 - (double)mind[m]);
            mind[m] = (float)best2;
        }
    }
}

// ---------------- zq (+)= T[idx]  (row gather); last stage also sums (z - zq)^2 ----------------
__global__ __launch_bounds__(256) void gather_k(const float* __restrict__ T,
                                                const int* __restrict__ idx,
                                                const float* __restrict__ z,
                                                float* __restrict__ zq,
                                                int stage0, int last,
                                                double* __restrict__ loss_acc) {
    __shared__ double red[256];
    int m = blockIdx.x * 16 + (threadIdx.x >> 4);
    int q = threadIdx.x & 15;
    const float* src = T + (size_t)idx[m] * CIN;
    float* dst = zq + (size_t)m * CIN;
    double s = 0.0;
    #pragma unroll
    for (int it = 0; it < 8; ++it) {
        int off = it * 64 + q * 4;
        float4 t = *reinterpret_cast<const float4*>(src + off);
        if (!stage0) {
            float4 o = *reinterpret_cast<const float4*>(dst + off);
            t.x += o.x; t.y += o.y; t.z += o.z; t.w += o.w;
        }
        *reinterpret_cast<float4*>(dst + off) = t;
        if (last) {
            float4 zv = *reinterpret_cast<const float4*>(z + (size_t)m * CIN + off);
            double d0 = (double)zv.x - (double)t.x;
            double d1 = (double)zv.y - (double)t.y;
            double d2 = (double)zv.z - (double)t.z;
            double d3 = (double)zv.w - (double)t.w;
            s += d0 * d0 + d1 * d1 + d2 * d2 + d3 * d3;
        }
    }
    if (last) {
        red[threadIdx.x] = s;
        __syncthreads();
        for (int off = 128; off > 0; off >>= 1) {
            if (threadIdx.x < off) red[threadIdx.x] += red[threadIdx.x + off];
            __syncthreads();
        }
        if (threadIdx.x == 0) atomicAdd(loss_acc + 1, red[0]);
    }
}

// ---------------- finalize ----------------
__global__ void final_k(const int* __restrict__ idx_sum,
                        const double* __restrict__ loss_acc,
                        float* __restrict__ out) {
    int i = blockIdx.x * blockDim.x + threadIdx.x;
    if (i < MTOK) out[MTOK * CIN + i] = (float)idx_sum[i];
    if (i == 0) {
        double loss = 2.0 * loss_acc[0] / (3.0 * (double)MTOK * (double)EMB)
                    + loss_acc[1] / ((double)MTOK * (double)CIN);
        out[MTOK * CIN + MTOK] = (float)loss;
    }
}

extern "C" void kernel_launch(void* const* d_in, const int* in_sizes, int n_in,
                              void* d_out, int out_size, void* d_ws, size_t ws_size,
                              hipStream_t stream) {
    const float* z     = (const float*)d_in[0];
    const float* W_in  = (const float*)d_in[1];
    const float* W_out = (const float*)d_in[2];
    const float* cbs   = (const float*)d_in[3];
    float* out = (float*)d_out;
    char* ws = (char*)d_ws;

    // ws layout (16B-aligned)
    double* vnorm64  = (double*)ws;                               // 24576
    double* loss_acc = (double*)(ws + 24576);                     // 16
    int*    cnt      = (int*)(ws + 24592);                        // 32 ([0..2] pair, [3..5] full)
    float*  vnorm32  = (float*)(ws + 24624);                      // 12288 -> 36912
    u16*    cbh      = (u16*)(ws + 36912);                        // 1572864 -> 1609776
    u16*    cbl      = (u16*)(ws + 1609776);                      // 1572864 -> 3182640
    u16*    wh       = (u16*)(ws + 3182640);                      // 786432 -> 3969072
    u16*    wl       = (u16*)(ws + 3969072);                      // 786432 -> 4755504
    float*  WinT     = (float*)(ws + 4755504);                    // 1572864 -> 6328368
    float*  T        = (float*)(ws + 6328368);                    // 6291456 -> 12619824
    float*  zi       = (float*)(ws + 12619824);                   // 33554432 -> 46174256
    char*   p        = ws + 46174256;
    int*    idx      = (int*)p;                                   // 131072
    int*    idx_sum  = (int*)(p + 131072);                        // 131072
    int*    flagged  = (int*)(p + 262144);                        // 131072
    float*  mind     = (float*)(p + 393216);                      // 131072
    int*    cand2    = (int*)(p + 524288);                        // 131072
    int*    fullList = (int*)(p + 655360);                        // 131072
    char*   q        = p + 786432;
    float*  pb1      = (float*)q;                                 // 262144 (2*MTOK)
    float*  pb2      = (float*)(q + 262144);                      // 262144
    float*  pb3      = (float*)(q + 524288);                      // 262144
    int*    pi1      = (int*)(q + 786432);                        // 262144
    int*    pi2      = (int*)(q + 1048576);                       // 262144

    float* zq = out;  // z_q lives in d_out[0 .. MTOK*CIN)

    init_k<<<dim3(1), dim3(1), 0, stream>>>(loss_acc, cnt);
    prep_cb_k<<<dim3(VQ * NCODE), dim3(64), 0, stream>>>(cbs, vnorm64, vnorm32, cbh, cbl);
    prep_w_k<<<dim3(VQ * EMB * CIN / 256), dim3(256), 0, stream>>>(W_in, wh, wl);
    prep_wt_k<<<dim3(VQ * EMB * CIN / 256), dim3(256), 0, stream>>>(W_in, WinT);
    prep_T_k<<<dim3(NCODE / 64, CIN / 64, VQ), dim3(256), 0, stream>>>(cbs, W_out, T);

    const int cumprod[VQ] = {1, 1024, 1024 * 1024};
    for (int i = 0; i < VQ; ++i) {
        const float* cb = cbs + (size_t)i * NCODE * EMB;
        zi_mfma_k<<<dim3(MTOK / 64), dim3(256), 0, stream>>>(
            z, zq, wh + (size_t)i * EMB * CIN, wl + (size_t)i * EMB * CIN,
            zi, loss_acc, i == 0 ? 1 : 0);
        pref_k<<<dim3(MTOK / 128, 2), dim3(256), 0, stream>>>(
            zi, cbh + (size_t)i * NCODE * EMB, cbl + (size_t)i * NCODE * EMB,
            vnorm32 + i * NCODE, pb1, pb2, pb3, pi1, pi2);
        merge_k<<<dim3(MTOK / 256), dim3(256), 0, stream>>>(
            pb1, pb2, pb3, pi1, pi2, idx, idx_sum, mind, flagged, cnt + i,
            fullList, cnt + 3 + i, cand2, loss_acc, i == 0 ? 1 : 0, cumprod[i]);
        rescan_pair_k<<<dim3(512), dim3(256), 0, stream>>>(
            z, zq, WinT + (size_t)i * EMB * CIN, cb, vnorm64 + i * NCODE,
            flagged, cnt + i, cand2, idx, idx_sum, mind, loss_acc, cumprod[i],
            i == 0 ? 1 : 0);
        fullscan_k<<<dim3(256), dim3(256), 0, stream>>>(
            z, zq, WinT + (size_t)i * EMB * CIN, cb, vnorm64 + i * NCODE,
            fullList, cnt + 3 + i, idx, idx_sum, mind, loss_acc, cumprod[i],
            i == 0 ? 1 : 0);
        gather_k<<<dim3(MTOK / 16), dim3(256), 0, stream>>>(
            T + (size_t)i * NCODE * CIN, idx, z, zq, i == 0 ? 1 : 0,
            i == VQ - 1 ? 1 : 0, loss_acc);
    }
    final_k<<<dim3(MTOK / 256), dim3(256), 0, stream>>>(idx_sum, loss_acc, out);
}

// Round 13
// 876.199 us; speedup vs baseline: 1.1727x; 1.1293x over previous
//
#include <hip/hip_runtime.h>

#define MTOK 32768   // 8*4096 tokens
#define CIN  512     // in_ch
#define EMB  256     // emb_ch
#define NCODE 1024
#define VQ   3
#define DELTA 2e-3f  // certified margin; worst-case approx score-diff error ~3e-4

typedef short s16x8 __attribute__((ext_vector_type(8)));
typedef float f32x4 __attribute__((ext_vector_type(4)));
typedef unsigned short u16;
typedef unsigned int u32;

static __device__ __forceinline__ u16 f2bf(float x) {
    unsigned int u = __float_as_uint(x);
    u += 0x7FFF + ((u >> 16) & 1);          // RNE
    return (u16)(u >> 16);
}
static __device__ __forceinline__ float bf2f(u16 h) {
    return __uint_as_float(((unsigned int)h) << 16);
}

// ---------------- init ----------------
__global__ void init_k(double* loss_acc, int* cnt) {
    loss_acc[0] = 0.0;  // sum of min-dists (znorm parts + score parts)
    loss_acc[1] = 0.0;  // sum (z - z_q)^2
    #pragma unroll
    for (int i = 0; i < 8; ++i) cnt[i] = 0;   // [0..2]=pair counts, [3..5]=full counts
}

// ---------------- codebook prep: ||v||^2 (fp64/fp32) + bf16 hi/lo split ----------------
__global__ __launch_bounds__(64) void prep_cb_k(const float* __restrict__ cbs,
                                                double* __restrict__ vnorm64,
                                                float* __restrict__ vnorm32,
                                                u16* __restrict__ cbh,
                                                u16* __restrict__ cbl) {
    int s = blockIdx.x;                       // 0 .. 3*NCODE-1
    const float* row = cbs + (size_t)s * EMB;
    double acc = 0.0;
    for (int k = threadIdx.x; k < EMB; k += 64) {
        float v = row[k];
        double vd = (double)v; acc += vd * vd;
        u16 h = f2bf(v);
        u16 l = f2bf(v - bf2f(h));
        cbh[(size_t)s * EMB + k] = h;
        cbl[(size_t)s * EMB + k] = l;
    }
    #pragma unroll
    for (int off = 32; off > 0; off >>= 1) acc += __shfl_down(acc, off, 64);
    if (threadIdx.x == 0) { vnorm64[s] = acc; vnorm32[s] = (float)acc; }
}

// ---------------- W_in bf16 hi/lo split ----------------
__global__ __launch_bounds__(256) void prep_w_k(const float* __restrict__ W_in,
                                                u16* __restrict__ wh,
                                                u16* __restrict__ wl) {
    int i = blockIdx.x * 256 + threadIdx.x;   // < VQ*EMB*CIN
    float v = W_in[i];
    u16 h = f2bf(v);
    wh[i] = h;
    wl[i] = f2bf(v - bf2f(h));
}

// ---------------- W_in transpose: WinT[s][k][e] = W_in[s][e][k] (exact fp32) ----------------
__global__ __launch_bounds__(256) void prep_wt_k(const float* __restrict__ W_in,
                                                 float* __restrict__ WinT) {
    int i = blockIdx.x * 256 + threadIdx.x;   // < VQ*EMB*CIN
    int s = i / (EMB * CIN);
    int rem = i - s * (EMB * CIN);
    int e = rem / CIN;
    int k = rem - e * CIN;
    WinT[(size_t)s * CIN * EMB + (size_t)k * EMB + e] = W_in[i];
}

// ---------------- T[s] = cb[s] @ W_out[s]^T  (fp64 acc, fp32 store) ----------------
__global__ __launch_bounds__(256) void prep_T_k(const float* __restrict__ cbs,
                                                const float* __restrict__ Wout,
                                                float* __restrict__ T) {
    const int stage = blockIdx.z;
    const float* A = cbs  + (size_t)stage * NCODE * EMB;
    const float* B = Wout + (size_t)stage * CIN * EMB;
    float* C = T + (size_t)stage * NCODE * CIN;
    __shared__ float As[64][33];
    __shared__ float Bs[64][33];
    const int tid = threadIdx.x;
    const int ty = tid >> 4, tx = tid & 15;
    const int m0 = blockIdx.x * 64;
    const int n0 = blockIdx.y * 64;
    const int lrow = tid >> 5, lcol = tid & 31;
    double acc[4][4];
    #pragma unroll
    for (int i = 0; i < 4; ++i)
        #pragma unroll
        for (int j = 0; j < 4; ++j) acc[i][j] = 0.0;

    for (int k0 = 0; k0 < EMB; k0 += 32) {
        __syncthreads();
        #pragma unroll
        for (int t = 0; t < 8; ++t) {
            int r = lrow + 8 * t;
            As[r][lcol] = A[(size_t)(m0 + r) * EMB + k0 + lcol];
            Bs[r][lcol] = B[(size_t)(n0 + r) * EMB + k0 + lcol];
        }
        __syncthreads();
        #pragma unroll
        for (int k = 0; k < 32; ++k) {
            double a[4], b[4];
            #pragma unroll
            for (int i = 0; i < 4; ++i) a[i] = (double)As[ty * 4 + i][k];
            #pragma unroll
            for (int j = 0; j < 4; ++j) b[j] = (double)Bs[tx * 4 + j][k];
            #pragma unroll
            for (int i = 0; i < 4; ++i)
                #pragma unroll
                for (int j = 0; j < 4; ++j) acc[i][j] += a[i] * b[j];
        }
    }
    #pragma unroll
    for (int i = 0; i < 4; ++i) {
        float4 v = make_float4((float)acc[i][0], (float)acc[i][1],
                               (float)acc[i][2], (float)acc[i][3]);
        *reinterpret_cast<float4*>(&C[(size_t)(m0 + ty * 4 + i) * CIN + n0 + tx * 4]) = v;
    }
}

// ================= FUSED: zi (bf16-split MFMA) + prefilter =================
// Block = 64 tokens (4 waves x 16). Phase 1: zi=(z-zq)@W^T, store bf16 h|l
// packed u32 to global (same-block read-back -> L2 hits). Phase 2: top-3
// prefilter over 1024 codes with LDS-staged codebook (same buffers as W).
__global__ __launch_bounds__(256, 2) void fused_k(const float* __restrict__ z,
                                                  const float* __restrict__ zq,
                                                  const u16* __restrict__ wh,
                                                  const u16* __restrict__ wl,
                                                  const u16* __restrict__ cbh,
                                                  const u16* __restrict__ cbl,
                                                  const float* __restrict__ vnorm32,
                                                  u32* __restrict__ zi_hl,
                                                  int* __restrict__ idx,
                                                  int* __restrict__ idx_sum,
                                                  float* __restrict__ mind,
                                                  int* __restrict__ flagged,
                                                  int* __restrict__ cnt,
                                                  int* __restrict__ fullList,
                                                  int* __restrict__ cntF,
                                                  int* __restrict__ cand2,
                                                  double* __restrict__ loss_acc,
                                                  int stage0, int cumprod) {
    __shared__ __align__(16) u16 sbh[2][16][264];
    __shared__ __align__(16) u16 sbl[2][16][264];
    __shared__ double loss_s[16];
    const int tid = threadIdx.x;
    const int w = tid >> 6;
    const int l = tid & 63;
    const int col = l & 15;
    const int g = l >> 4;
    const int mw = blockIdx.x * 64 + w * 16;
    const int sr = tid >> 4, sq = tid & 15;

    // ---------- Phase 1: A fragments from z - zq ----------
    {
        s16x8 ah[16], al[16];
        const float* zr = z  + (size_t)(mw + col) * CIN + g * 8;
        const float* qr = zq + (size_t)(mw + col) * CIN + g * 8;
        #pragma unroll
        for (int kc = 0; kc < 16; ++kc) {
            float4 f0 = *reinterpret_cast<const float4*>(zr + kc * 32);
            float4 f1 = *reinterpret_cast<const float4*>(zr + kc * 32 + 4);
            float f[8] = {f0.x, f0.y, f0.z, f0.w, f1.x, f1.y, f1.z, f1.w};
            if (!stage0) {
                float4 q0 = *reinterpret_cast<const float4*>(qr + kc * 32);
                float4 q1 = *reinterpret_cast<const float4*>(qr + kc * 32 + 4);
                f[0] -= q0.x; f[1] -= q0.y; f[2] -= q0.z; f[3] -= q0.w;
                f[4] -= q1.x; f[5] -= q1.y; f[6] -= q1.z; f[7] -= q1.w;
            }
            #pragma unroll
            for (int j = 0; j < 8; ++j) {
                u16 h = f2bf(f[j]);
                u16 lo = f2bf(f[j] - bf2f(h));
                ah[kc][j] = (short)h; al[kc][j] = (short)lo;
            }
        }

        // W staging: tile nt = 16 neurons x 512 k, split into two 256-k slots.
        const u16* gwh = wh + (size_t)sr * CIN + sq * 8;
        const u16* gwl = wl + (size_t)sr * CIN + sq * 8;
        uint4 h0, h1, h2, h3, l0, l1, l2, l3;
#define WLOAD(NT) do { const u16* th = gwh + (size_t)(NT) * (16 * CIN);               \
    const u16* tl = gwl + (size_t)(NT) * (16 * CIN);                                  \
    h0 = *(const uint4*)(th);        h1 = *(const uint4*)(th + 128);                  \
    h2 = *(const uint4*)(th + 256);  h3 = *(const uint4*)(th + 384);                  \
    l0 = *(const uint4*)(tl);        l1 = *(const uint4*)(tl + 128);                  \
    l2 = *(const uint4*)(tl + 256);  l3 = *(const uint4*)(tl + 384); } while (0)
#define WWRITE() do {                                                                 \
    *(uint4*)&sbh[0][sr][sq * 8]       = h0;  *(uint4*)&sbh[0][sr][sq * 8 + 128] = h1;\
    *(uint4*)&sbh[1][sr][sq * 8]       = h2;  *(uint4*)&sbh[1][sr][sq * 8 + 128] = h3;\
    *(uint4*)&sbl[0][sr][sq * 8]       = l0;  *(uint4*)&sbl[0][sr][sq * 8 + 128] = l1;\
    *(uint4*)&sbl[1][sr][sq * 8]       = l2;  *(uint4*)&sbl[1][sr][sq * 8 + 128] = l3;\
    } while (0)
        WLOAD(0);

        double zn = 0.0;
        for (int nt = 0; nt < 16; ++nt) {
            __syncthreads();                     // prev tile reads done
            WWRITE();
            __syncthreads();                     // tile nt ready
            if (nt + 1 < 16) WLOAD(nt + 1);      // issue-early (T14)
            f32x4 a0 = {0.f, 0.f, 0.f, 0.f};
            f32x4 a1 = {0.f, 0.f, 0.f, 0.f};
            f32x4 a2 = {0.f, 0.f, 0.f, 0.f};
            #pragma unroll
            for (int kc = 0; kc < 16; ++kc) {
                const int p = kc >> 3;
                const int ko = (kc & 7) * 32 + g * 8;
                s16x8 Bh = *(const s16x8*)&sbh[p][col][ko];
                s16x8 Bl = *(const s16x8*)&sbl[p][col][ko];
                a0 = __builtin_amdgcn_mfma_f32_16x16x32_bf16(ah[kc], Bh, a0, 0, 0, 0);
                a1 = __builtin_amdgcn_mfma_f32_16x16x32_bf16(al[kc], Bh, a1, 0, 0, 0);
                a2 = __builtin_amdgcn_mfma_f32_16x16x32_bf16(ah[kc], Bl, a2, 0, 0, 0);
            }
            #pragma unroll
            for (int r = 0; r < 4; ++r) {
                float v = a0[r] + a1[r] + a2[r];
                u16 h = f2bf(v);
                u16 lo = f2bf(v - bf2f(h));
                zi_hl[(size_t)(mw + g * 4 + r) * EMB + nt * 16 + col] =
                    (u32)h | ((u32)lo << 16);
                zn += (double)v * (double)v;
            }
        }
#undef WLOAD
#undef WWRITE
        #pragma unroll
        for (int off = 32; off > 0; off >>= 1) zn += __shfl_down(zn, off, 64);
        if (l == 0) atomicAdd(loss_acc, zn);
    }
    __syncthreads();   // drain zi_hl stores (vmcnt 0 before barrier); W reads done

    // ---------- Phase 2: prefilter ----------
    s16x8 ah[8], al[8];
    {
        const u32* zr = zi_hl + (size_t)(mw + col) * EMB + g * 8;
        #pragma unroll
        for (int kc = 0; kc < 8; ++kc) {
            uint4 u0 = *reinterpret_cast<const uint4*>(zr + kc * 32);
            uint4 u1 = *reinterpret_cast<const uint4*>(zr + kc * 32 + 4);
            u32 u[8] = {u0.x, u0.y, u0.z, u0.w, u1.x, u1.y, u1.z, u1.w};
            #pragma unroll
            for (int j = 0; j < 8; ++j) {
                ah[kc][j] = (short)(u[j] & 0xffffu);
                al[kc][j] = (short)(u[j] >> 16);
            }
        }
    }

    float b1[4] = {1e30f, 1e30f, 1e30f, 1e30f};
    float b2[4] = {1e30f, 1e30f, 1e30f, 1e30f};
    float b3[4] = {1e30f, 1e30f, 1e30f, 1e30f};
    int   i1[4] = {0, 0, 0, 0};
    int   i2[4] = {0, 0, 0, 0};

    const u16* gh = cbh + (size_t)sr * EMB + sq * 8;
    const u16* gl = cbl + (size_t)sr * EMB + sq * 8;
    uint4 h0, h1, l0, l1;
#define PLOAD(CT) do { const u16* th = gh + (size_t)(CT) * (16 * EMB);                \
    const u16* tl = gl + (size_t)(CT) * (16 * EMB);                                   \
    h0 = *(const uint4*)(th);  h1 = *(const uint4*)(th + 128);                        \
    l0 = *(const uint4*)(tl);  l1 = *(const uint4*)(tl + 128); } while (0)
#define PWRITE(P) do {                                                                \
    *(uint4*)&sbh[P][sr][sq * 8] = h0;  *(uint4*)&sbh[P][sr][sq * 8 + 128] = h1;      \
    *(uint4*)&sbl[P][sr][sq * 8] = l0;  *(uint4*)&sbl[P][sr][sq * 8 + 128] = l1;      \
    } while (0)
    PLOAD(0); PWRITE(0); PLOAD(1);

    for (int ct = 0; ct < 64; ++ct) {
        __syncthreads();                         // buf[ct&1] ready; prev reads done
        const int p = ct & 1;
        if (ct + 1 < 64) PWRITE((ct + 1) & 1);
        if (ct + 2 < 64) PLOAD(ct + 2);
        const float vn = vnorm32[ct * 16 + col];
        f32x4 a0 = {0.f, 0.f, 0.f, 0.f};
        f32x4 a1 = {0.f, 0.f, 0.f, 0.f};
        f32x4 a2 = {0.f, 0.f, 0.f, 0.f};
        #pragma unroll
        for (int kc = 0; kc < 8; ++kc) {
            s16x8 Bh = *(const s16x8*)&sbh[p][col][g * 8 + kc * 32];
            s16x8 Bl = *(const s16x8*)&sbl[p][col][g * 8 + kc * 32];
            a0 = __builtin_amdgcn_mfma_f32_16x16x32_bf16(ah[kc], Bh, a0, 0, 0, 0);
            a1 = __builtin_amdgcn_mfma_f32_16x16x32_bf16(al[kc], Bh, a1, 0, 0, 0);
            a2 = __builtin_amdgcn_mfma_f32_16x16x32_bf16(ah[kc], Bl, a2, 0, 0, 0);
        }
        #pragma unroll
        for (int r = 0; r < 4; ++r) {
            float sc = vn - 2.f * (a0[r] + a1[r] + a2[r]);
            int c = ct * 16 + col;
            if (sc < b1[r]) { b3[r] = b2[r]; b2[r] = b1[r]; i2[r] = i1[r]; b1[r] = sc; i1[r] = c; }
            else if (sc < b2[r]) { b3[r] = b2[r]; b2[r] = sc; i2[r] = c; }
            else b3[r] = fminf(b3[r], sc);
        }
    }
#undef PLOAD
#undef PWRITE

    // cross-lane top-3 merge over the 16 lanes of each token group
    #pragma unroll
    for (int off = 1; off < 16; off <<= 1) {
        #pragma unroll
        for (int r = 0; r < 4; ++r) {
            float c1 = __shfl_xor(b1[r], off, 64);
            int   j1 = __shfl_xor(i1[r], off, 64);
            float c2 = __shfl_xor(b2[r], off, 64);
            int   j2 = __shfl_xor(i2[r], off, 64);
            float c3 = __shfl_xor(b3[r], off, 64);
            float nb1, nb2, nb3; int ni1, ni2;
            if (c1 < b1[r] || (c1 == b1[r] && j1 < i1[r])) {
                nb1 = c1; ni1 = j1;
                if (b1[r] < c2 || (b1[r] == c2 && i1[r] < j2)) {
                    nb2 = b1[r]; ni2 = i1[r]; nb3 = fminf(b2[r], c2);
                } else {
                    nb2 = c2; ni2 = j2; nb3 = fminf(b1[r], c3);
                }
            } else {
                nb1 = b1[r]; ni1 = i1[r];
                if (c1 < b2[r] || (c1 == b2[r] && j1 < i2[r])) {
                    nb2 = c1; ni2 = j1; nb3 = fminf(b2[r], c2);
                } else {
                    nb2 = b2[r]; ni2 = i2[r]; nb3 = fminf(c1, b3[r]);
                }
            }
            b1[r] = nb1; b2[r] = nb2; b3[r] = nb3; i1[r] = ni1; i2[r] = ni2;
        }
    }
    if (col == 0) {
        double lsum = 0.0;
        #pragma unroll
        for (int r = 0; r < 4; ++r) {
            int m = mw + g * 4 + r;
            idx[m] = i1[r];
            if (stage0) idx_sum[m] = i1[r];
            else        idx_sum[m] += i1[r] * cumprod;
            mind[m] = b1[r];                 // score-only part
            lsum += (double)b1[r];
            if (b2[r] - b1[r] < DELTA) {
                if (b3[r] - b1[r] < DELTA) {
                    int slot = atomicAdd(cntF, 1);
                    fullList[slot] = m;
                } else {
                    int slot = atomicAdd(cnt, 1);
                    flagged[slot] = m;
                    cand2[m] = i2[r];
                }
            }
        }
        loss_s[w * 4 + g] = lsum;
    }
    __syncthreads();
    if (tid == 0) {
        double s = 0.0;
        #pragma unroll
        for (int q = 0; q < 16; ++q) s += loss_s[q];
        atomicAdd(loss_acc, s);
    }
}

// ---------------- exact fp64 pair rescan, batched 8 tokens/block ----------------
__global__ __launch_bounds__(256) void rescan_pair_k(const float* __restrict__ z,
                                                     const float* __restrict__ zqv,
                                                     const float* __restrict__ WinT,
                                                     const float* __restrict__ cb,
                                                     const double* __restrict__ vnorm64,
                                                     const int* __restrict__ flagged,
                                                     const int* __restrict__ cnt,
                                                     const int* __restrict__ cand2,
                                                     int* __restrict__ idx,
                                                     int* __restrict__ idx_sum,
                                                     float* __restrict__ mind,
                                                     double* __restrict__ loss_acc,
                                                     int cumprod, int stage0) {
    __shared__ double r64[8][CIN];           // 32 KB; first 16 KB reused as zi64[8][256]
    __shared__ int mArr[8], cAArr[8], cBArr[8];
    double* zi_l = &r64[0][0];               // alias (used after sync)
    const int tid = threadIdx.x;
    const int w = tid >> 6, l = tid & 63;
    const int n = *cnt;

    for (int jb = blockIdx.x; jb * 8 < n; jb += gridDim.x) {
        const int nt = min(8, n - jb * 8);
        __syncthreads();                     // protect LDS reuse across jb
        if (tid < nt) {
            int m = flagged[jb * 8 + tid];
            mArr[tid] = m;
            cAArr[tid] = idx[m]; cBArr[tid] = cand2[m];
        }
        __syncthreads();
        // stage residuals (coalesced): thread covers k = tid, tid+256
        for (int t = 0; t < nt; ++t) {
            const int m = mArr[t];
            #pragma unroll
            for (int h = 0; h < 2; ++h) {
                int k = tid + h * 256;
                float rv = z[(size_t)m * CIN + k];
                if (!stage0) rv -= zqv[(size_t)m * CIN + k];   // fp32 subtract (matches ref)
                r64[t][k] = (double)rv;
            }
        }
        __syncthreads();
        // zi64: thread e = tid computes 8 dots; WinT rows read coalesced, r64 broadcast
        double acc[8] = {0, 0, 0, 0, 0, 0, 0, 0};
        #pragma unroll 4
        for (int k = 0; k < CIN; ++k) {
            double wv = (double)WinT[(size_t)k * EMB + tid];
            #pragma unroll
            for (int t = 0; t < 8; ++t) acc[t] += r64[t][k] * wv;
        }
        __syncthreads();
        #pragma unroll
        for (int t = 0; t < 8; ++t) zi_l[t * 256 + tid] = acc[t];
        __syncthreads();

        // wave w handles tokens t = w, w+4
        for (int t = w; t < nt; t += 4) {
            const int cA = cAArr[t], cB = cBArr[t], m = mArr[t];
            const double* zt = zi_l + t * 256;
            float4 vA = *(const float4*)(cb + (size_t)cA * EMB + 4 * l);
            float4 vB = *(const float4*)(cb + (size_t)cB * EMB + 4 * l);
            double z0 = zt[4 * l], z1 = zt[4 * l + 1];
            double z2 = zt[4 * l + 2], z3 = zt[4 * l + 3];
            double sA = z0 * (double)vA.x + z1 * (double)vA.y
                      + z2 * (double)vA.z + z3 * (double)vA.w;
            double sB = z0 * (double)vB.x + z1 * (double)vB.y
                      + z2 * (double)vB.z + z3 * (double)vB.w;
            #pragma unroll
            for (int off = 1; off < 64; off <<= 1) {
                sA += __shfl_xor(sA, off, 64);
                sB += __shfl_xor(sB, off, 64);
            }
            if (l == 0) {
                double dA = vnorm64[cA] - 2.0 * sA;
                double dB = vnorm64[cB] - 2.0 * sB;
                int bi; double best;
                if (dB < dA || (dB == dA && cB < cA)) { bi = cB; best = dB; }
                else                                   { bi = cA; best = dA; }
                int oldI = idx[m];
                if (bi != oldI) { idx[m] = bi; idx_sum[m] += (bi - oldI) * cumprod; }
                atomicAdd(loss_acc, best - (double)mind[m]);
                mind[m] = (float)best;
            }
        }
    }
}

// ---------------- exact fp64 full scan, one block per full token, thread-per-code ----------------
__global__ __launch_bounds__(256) void fullscan_k(const float* __restrict__ z,
                                                  const float* __restrict__ zqv,
                                                  const float* __restrict__ WinT,
                                                  const float* __restrict__ cb,
                                                  const double* __restrict__ vnorm64,
                                                  const int* __restrict__ fullList,
                                                  const int* __restrict__ cntF,
                                                  int* __restrict__ idx,
                                                  int* __restrict__ idx_sum,
                                                  float* __restrict__ mind,
                                                  double* __restrict__ loss_acc,
                                                  int cumprod, int stage0) {
    __shared__ double r64[CIN];
    __shared__ double zi64[EMB];
    __shared__ double sred[256];
    __shared__ int ired[256];
    const int tid = threadIdx.x;
    const int n = *cntF;

    for (int j = blockIdx.x; j < n; j += gridDim.x) {
        const int m = fullList[j];
        __syncthreads();                     // protect LDS reuse across j
        #pragma unroll
        for (int h = 0; h < 2; ++h) {
            int k = tid + h * 256;
            float rv = z[(size_t)m * CIN + k];
            if (!stage0) rv -= zqv[(size_t)m * CIN + k];
            r64[k] = (double)rv;
        }
        __syncthreads();
        {
            double acc = 0.0;
            #pragma unroll 8
            for (int k = 0; k < CIN; ++k)
                acc += r64[k] * (double)WinT[(size_t)k * EMB + tid];
            zi64[tid] = acc;
        }
        __syncthreads();
        // thread t scores codes {t, 256+t, 512+t, 768+t} (ascending per thread)
        double best = 1e300; int bi = 0;
        #pragma unroll
        for (int q = 0; q < 4; ++q) {
            const int c = q * 256 + tid;
            const float* row = cb + (size_t)c * EMB;
            double s0 = 0, s1 = 0, s2 = 0, s3 = 0;
            #pragma unroll 4
            for (int e = 0; e < EMB; e += 4) {
                float4 v = *(const float4*)(row + e);
                s0 += zi64[e]     * (double)v.x;
                s1 += zi64[e + 1] * (double)v.y;
                s2 += zi64[e + 2] * (double)v.z;
                s3 += zi64[e + 3] * (double)v.w;
            }
            double sc = vnorm64[c] - 2.0 * ((s0 + s1) + (s2 + s3));
            if (sc < best) { best = sc; bi = c; }
        }
        sred[tid] = best; ired[tid] = bi;
        __syncthreads();
        for (int off = 128; off > 0; off >>= 1) {
            if (tid < off) {
                double ob = sred[tid + off]; int oi = ired[tid + off];
                if (ob < sred[tid] || (ob == sred[tid] && oi < ired[tid])) {
                    sred[tid] = ob; ired[tid] = oi;
                }
            }
            __syncthreads();
        }
        if (tid == 0) {
            int oldI = idx[m], bi2 = ired[0];
            double best2 = sred[0];
            if (bi2 != oldI) { idx[m] = bi2; idx_sum[m] += (bi2 - oldI) * cumprod; }
            atomicAdd(loss_acc, best2 - (double)mind[m]);
            mind[m] = (float)best2;
        }
    }
}

// ---------------- zq (+)= T[idx]  (row gather); last stage also sums (z - zq)^2 ----------------
__global__ __launch_bounds__(256) void gather_k(const float* __restrict__ T,
                                                const int* __restrict__ idx,
                                                const float* __restrict__ z,
                                                float* __restrict__ zq,
                                                int stage0, int last,
                                                double* __restrict__ loss_acc) {
    __shared__ double red[256];
    int m = blockIdx.x * 16 + (threadIdx.x >> 4);
    int q = threadIdx.x & 15;
    const float* src = T + (size_t)idx[m] * CIN;
    float* dst = zq + (size_t)m * CIN;
    double s = 0.0;
    #pragma unroll
    for (int it = 0; it < 8; ++it) {
        int off = it * 64 + q * 4;
        float4 t = *reinterpret_cast<const float4*>(src + off);
        if (!stage0) {
            float4 o = *reinterpret_cast<const float4*>(dst + off);
            t.x += o.x; t.y += o.y; t.z += o.z; t.w += o.w;
        }
        *reinterpret_cast<float4*>(dst + off) = t;
        if (last) {
            float4 zv = *reinterpret_cast<const float4*>(z + (size_t)m * CIN + off);
            double d0 = (double)zv.x - (double)t.x;
            double d1 = (double)zv.y - (double)t.y;
            double d2 = (double)zv.z - (double)t.z;
            double d3 = (double)zv.w - (double)t.w;
            s += d0 * d0 + d1 * d1 + d2 * d2 + d3 * d3;
        }
    }
    if (last) {
        red[threadIdx.x] = s;
        __syncthreads();
        for (int off = 128; off > 0; off >>= 1) {
            if (threadIdx.x < off) red[threadIdx.x] += red[threadIdx.x + off];
            __syncthreads();
        }
        if (threadIdx.x == 0) atomicAdd(loss_acc + 1, red[0]);
    }
}

// ---------------- finalize ----------------
__global__ void final_k(const int* __restrict__ idx_sum,
                        const double* __restrict__ loss_acc,
                        float* __restrict__ out) {
    int i = blockIdx.x * blockDim.x + threadIdx.x;
    if (i < MTOK) out[MTOK * CIN + i] = (float)idx_sum[i];
    if (i == 0) {
        double loss = 2.0 * loss_acc[0] / (3.0 * (double)MTOK * (double)EMB)
                    + loss_acc[1] / ((double)MTOK * (double)CIN);
        out[MTOK * CIN + MTOK] = (float)loss;
    }
}

extern "C" void kernel_launch(void* const* d_in, const int* in_sizes, int n_in,
                              void* d_out, int out_size, void* d_ws, size_t ws_size,
                              hipStream_t stream) {
    const float* z     = (const float*)d_in[0];
    const float* W_in  = (const float*)d_in[1];
    const float* W_out = (const float*)d_in[2];
    const float* cbs   = (const float*)d_in[3];
    float* out = (float*)d_out;
    char* ws = (char*)d_ws;

    // ws layout (16B-aligned)
    double* vnorm64  = (double*)ws;                               // 24576
    double* loss_acc = (double*)(ws + 24576);                     // 16
    int*    cnt      = (int*)(ws + 24592);                        // 32 ([0..2] pair, [3..5] full)
    float*  vnorm32  = (float*)(ws + 24624);                      // 12288 -> 36912
    u16*    cbh      = (u16*)(ws + 36912);                        // 1572864 -> 1609776
    u16*    cbl      = (u16*)(ws + 1609776);                      // 1572864 -> 3182640
    u16*    wh       = (u16*)(ws + 3182640);                      // 786432 -> 3969072
    u16*    wl       = (u16*)(ws + 3969072);                      // 786432 -> 4755504
    float*  WinT     = (float*)(ws + 4755504);                    // 1572864 -> 6328368
    float*  T        = (float*)(ws + 6328368);                    // 6291456 -> 12619824
    u32*    zi_hl    = (u32*)(ws + 12619824);                     // 33554432 -> 46174256
    char*   p        = ws + 46174256;
    int*    idx      = (int*)p;                                   // 131072
    int*    idx_sum  = (int*)(p + 131072);                        // 131072
    int*    flagged  = (int*)(p + 262144);                        // 131072
    float*  mind     = (float*)(p + 393216);                      // 131072
    int*    cand2    = (int*)(p + 524288);                        // 131072
    int*    fullList = (int*)(p + 655360);                        // 131072

    float* zq = out;  // z_q lives in d_out[0 .. MTOK*CIN)

    init_k<<<dim3(1), dim3(1), 0, stream>>>(loss_acc, cnt);
    prep_cb_k<<<dim3(VQ * NCODE), dim3(64), 0, stream>>>(cbs, vnorm64, vnorm32, cbh, cbl);
    prep_w_k<<<dim3(VQ * EMB * CIN / 256), dim3(256), 0, stream>>>(W_in, wh, wl);
    prep_wt_k<<<dim3(VQ * EMB * CIN / 256), dim3(256), 0, stream>>>(W_in, WinT);
    prep_T_k<<<dim3(NCODE / 64, CIN / 64, VQ), dim3(256), 0, stream>>>(cbs, W_out, T);

    const int cumprod[VQ] = {1, 1024, 1024 * 1024};
    for (int i = 0; i < VQ; ++i) {
        const float* cb = cbs + (size_t)i * NCODE * EMB;
        fused_k<<<dim3(MTOK / 64), dim3(256), 0, stream>>>(
            z, zq, wh + (size_t)i * EMB * CIN, wl + (size_t)i * EMB * CIN,
            cbh + (size_t)i * NCODE * EMB, cbl + (size_t)i * NCODE * EMB,
            vnorm32 + i * NCODE, zi_hl, idx, idx_sum, mind, flagged, cnt + i,
            fullList, cnt + 3 + i, cand2, loss_acc, i == 0 ? 1 : 0, cumprod[i]);
        rescan_pair_k<<<dim3(512), dim3(256), 0, stream>>>(
            z, zq, WinT + (size_t)i * EMB * CIN, cb, vnorm64 + i * NCODE,
            flagged, cnt + i, cand2, idx, idx_sum, mind, loss_acc, cumprod[i],
            i == 0 ? 1 : 0);
        fullscan_k<<<dim3(256), dim3(256), 0, stream>>>(
            z, zq, WinT + (size_t)i * EMB * CIN, cb, vnorm64 + i * NCODE,
            fullList, cnt + 3 + i, idx, idx_sum, mind, loss_acc, cumprod[i],
            i == 0 ? 1 : 0);
        gather_k<<<dim3(MTOK / 16), dim3(256), 0, stream>>>(
            T + (size_t)i * NCODE * CIN, idx, z, zq, i == 0 ? 1 : 0,
            i == VQ - 1 ? 1 : 0, loss_acc);
    }
    final_k<<<dim3(MTOK / 256), dim3(256), 0, stream>>>(idx_sum, loss_acc, out);
}